// Round 6
// baseline (227.345 us; speedup 1.0000x reference)
//
#include <hip/hip_runtime.h>
#include <stdint.h>

typedef __attribute__((ext_vector_type(8))) short bf16x8;
typedef __attribute__((ext_vector_type(4))) short s16x4;
typedef __attribute__((ext_vector_type(4))) float f32x4;
typedef __attribute__((ext_vector_type(16))) float f32x16;
typedef __attribute__((ext_vector_type(2))) unsigned u32x2;

#define DEVI __device__ __forceinline__

constexpr int B_ = 4, S_ = 2048, D_ = 1024, H_ = 16, DK_ = 64;
constexpr int M_ = B_ * S_;  // 8192 rows total

DEVI short f2bf(float f) {
  union { float f; uint32_t u; } x; x.f = f;
  uint32_t r = x.u + 0x7fffu + ((x.u >> 16) & 1u);  // RNE
  return (short)(uint16_t)(r >> 16);
}
DEVI float exp2_hw(float x) {  // v_exp_f32 is 2^x
  float r; asm("v_exp_f32 %0, %1" : "=v"(r) : "v"(x)); return r;
}
DEVI uint32_t cvtpk(float lo, float hi) {  // [15:0]=bf16(lo), [31:16]=bf16(hi)
  uint32_t r; asm("v_cvt_pk_bf16_f32 %0, %1, %2" : "=v"(r) : "v"(lo), "v"(hi));
  return r;
}
// cross-half swap: a' = {a.lo, b.lo(partner)}, b' = {a.hi(partner), b.hi}
#if __has_builtin(__builtin_amdgcn_permlane32_swap)
DEVI void plswap(uint32_t& a, uint32_t& b) {
  u32x2 r = __builtin_amdgcn_permlane32_swap(a, b, false, false);
  a = r[0]; b = r[1];
}
#else
DEVI void plswap(uint32_t& a, uint32_t& b) {
  const int h = (threadIdx.x & 63) >> 5;
  const uint32_t pa = (uint32_t)__shfl_xor((int)a, 32);
  const uint32_t pb = (uint32_t)__shfl_xor((int)b, 32);
  const uint32_t na = h ? pb : a;
  const uint32_t nb = h ? b : pa;
  a = na; b = nb;
}
#endif
DEVI void gload16(const short* g, short* l) {
  __builtin_amdgcn_global_load_lds((const __attribute__((address_space(1))) uint32_t*)g,
                                   (__attribute__((address_space(3))) uint32_t*)l, 16, 0, 0);
}

// ---------------- fp32 -> bf16 conversion, up to 4 same-size tensors ----------
template <int LOG2G>
__global__ __launch_bounds__(256) void cvt3(const float* __restrict__ s0,
                                            const float* __restrict__ s1,
                                            const float* __restrict__ s2,
                                            const float* __restrict__ s3,
                                            short* __restrict__ d0,
                                            short* __restrict__ d1,
                                            short* __restrict__ d2,
                                            short* __restrict__ d3,
                                            int narr) {
  const int stride = gridDim.x * blockDim.x;
  const int total = narr << LOG2G;
  for (int g = blockIdx.x * blockDim.x + threadIdx.x; g < total; g += stride) {
    const int a = g >> LOG2G;
    const size_t off = (size_t)(g & ((1 << LOG2G) - 1)) * 8;
    const float* src = (a == 0) ? s0 : (a == 1) ? s1 : (a == 2) ? s2 : s3;
    short* dst = (a == 0) ? d0 : (a == 1) ? d1 : (a == 2) ? d2 : d3;
    const f32x4 x = *(const f32x4*)(src + off);
    const f32x4 y = *(const f32x4*)(src + off + 4);
    bf16x8 o;
#pragma unroll
    for (int e = 0; e < 4; ++e) { o[e] = f2bf(x[e]); o[e + 4] = f2bf(y[e]); }
    *(bf16x8*)(dst + off) = o;
  }
}

// ---------------- bf16 GEMM: C[m,n] = (sum_k A[m,k]*W[n,k] + bias)*scale ------
// 128x128 tile, BK=32, 4 waves, 16x16x32 MFMA. 2-phase dbuf + XOR chunk swizzle.
// MODE 0: bf16 row-major out. MODE 1: f32 row-major out.
// MODE 2: bf16 out transposed into Vt[(b*1024+n)][s] (s = m % 2048), rows S_.
template <int MODE>
__global__ __launch_bounds__(256) void gemm_bt(const short* __restrict__ A,
                                               const short* __restrict__ Bw,
                                               const float* __restrict__ bias,
                                               void* __restrict__ Cout,
                                               int Kdim, int Ndim, float scale) {
  __shared__ short sA[2][128 * 32];
  __shared__ short sB[2][128 * 32];
  const int tid = threadIdx.x;
  const int wid = tid >> 6, lane = tid & 63;
  const int m0 = blockIdx.x * 128, n0 = blockIdx.y * 128;
  const int wm = wid >> 1, wn = wid & 1;

  f32x4 acc[4][4];
#pragma unroll
  for (int i = 0; i < 4; ++i)
#pragma unroll
    for (int j = 0; j < 4; ++j) acc[i][j] = (f32x4){0.f, 0.f, 0.f, 0.f};

  const int srow = wid * 32 + (lane >> 2);
  const int swzs = (srow & 3) ^ ((srow >> 2) & 3);
  const int scol = ((lane & 3) ^ swzs) * 8;
  const short* gA = A + (size_t)(m0 + srow) * Kdim + scol;
  const short* gB = Bw + (size_t)(n0 + srow) * Kdim + scol;

  auto STAGE = [&](int bi, int kt) {
    short* la = &sA[bi][(wid * 32) * 32];
    short* lb = &sB[bi][(wid * 32) * 32];
    gload16(gA + kt, la);
    gload16(gA + (size_t)16 * Kdim + kt, la + 16 * 32);
    gload16(gB + kt, lb);
    gload16(gB + (size_t)16 * Kdim + kt, lb + 16 * 32);
  };

  STAGE(0, 0);
  __syncthreads();
  int cur = 0;

  const int swzf = (lane & 3) ^ ((lane >> 2) & 3);
  const int cofs = (((lane >> 4) ^ swzf) << 3);

  for (int kt = 0; kt < Kdim; kt += 32) {
    if (kt + 32 < Kdim) STAGE(cur ^ 1, kt + 32);
    bf16x8 af[4], bfr[4];
#pragma unroll
    for (int mf = 0; mf < 4; ++mf)
      af[mf] = *(const bf16x8*)&sA[cur][(wm * 64 + mf * 16 + (lane & 15)) * 32 + cofs];
#pragma unroll
    for (int nf = 0; nf < 4; ++nf)
      bfr[nf] = *(const bf16x8*)&sB[cur][(wn * 64 + nf * 16 + (lane & 15)) * 32 + cofs];
#pragma unroll
    for (int mf = 0; mf < 4; ++mf)
#pragma unroll
      for (int nf = 0; nf < 4; ++nf)
        acc[mf][nf] = __builtin_amdgcn_mfma_f32_16x16x32_bf16(af[mf], bfr[nf], acc[mf][nf], 0, 0, 0);
    __syncthreads();
    cur ^= 1;
  }

#pragma unroll
  for (int mf = 0; mf < 4; ++mf) {
#pragma unroll
    for (int nf = 0; nf < 4; ++nf) {
      const int n = n0 + wn * 64 + nf * 16 + (lane & 15);
      const float bi = bias[n];
      if (MODE == 2) {
        const int m_base = m0 + wm * 64 + mf * 16 + ((lane >> 4) * 4);
        const int b = m_base >> 11, s0 = m_base & 2047;
        s16x4 pk;
#pragma unroll
        for (int r = 0; r < 4; ++r) pk[r] = f2bf(acc[mf][nf][r] + bi);
        *(s16x4*)((short*)Cout + ((size_t)(b * 1024 + n)) * 2048 + s0) = pk;
      } else {
#pragma unroll
        for (int r = 0; r < 4; ++r) {
          const int m = m0 + wm * 64 + mf * 16 + ((lane >> 4) * 4) + r;
          const float vv = (acc[mf][nf][r] + bi) * scale;
          if (MODE == 0)
            ((short*)Cout)[(size_t)m * Ndim + n] = f2bf(vv);
          else
            ((float*)Cout)[(size_t)m * Ndim + n] = vv;
        }
      }
    }
  }
}

// ---------------- causal flash attention --------------------------------------
// 8 waves x 32 q-rows, causal load-pairing (waves 0-3: panel 15-pi, 4-7: pi).
// 32x32x16 MFMA swapped operands; K/V frags fully preloaded (ILP); cross-half
// P exchange via permlane32_swap builtin; tree reductions + shfl_xor(32);
// wave-uniform defer-max; 2-phase dbuf staging.
__global__ __launch_bounds__(512, 4) void attn_fwd(const short* __restrict__ Qf,
                                                   const short* __restrict__ Kf,
                                                   const short* __restrict__ Vt,
                                                   short* __restrict__ AO) {
  __shared__ short sK[2][64 * 64];   // [key][d], swizzled chunks
  __shared__ short sV[2][64 * 64];   // [d][key], swizzled chunks

  const int tid = threadIdx.x, wid = tid >> 6, lane = tid & 63;
  const int h = lane >> 5, ql = lane & 31;
  const int cpx = gridDim.x >> 3;
  const int wg = ((int)blockIdx.x & 7) * cpx + ((int)blockIdx.x >> 3);
  const int bh = wg >> 3;
  const int pi = wg & 7;
  const int b = bh >> 4, hd = bh & 15;
  const int panel = (wid < 4) ? (15 - pi) : pi;
  const int qw = panel * 128 + (wid & 3) * 32;
  const int qg = qw + ql;
  const size_t rowbase = (size_t)b * S_ * D_ + (size_t)hd * DK_;
  const size_t vbase = (size_t)bh * 64 * S_;

  bf16x8 aQ[4];
  {
    const short* qp = Qf + rowbase + (size_t)qg * D_ + h * 8;
#pragma unroll
    for (int d = 0; d < 4; ++d) aQ[d] = *(const bf16x8*)(qp + d * 16);
  }

  f32x16 o0, o1;
#pragma unroll
  for (int i = 0; i < 16; ++i) { o0[i] = 0.f; o1[i] = 0.f; }
  float m_run = -1e30f, lsum = 0.f;

  const int srow8 = lane >> 3;
  const int schunk = ((lane & 7) ^ srow8) * 8;
  const short* gK = Kf + rowbase + (size_t)(wid * 8 + srow8) * D_ + schunk;
  const short* gV = Vt + vbase + (size_t)(wid * 8 + srow8) * S_ + schunk;

  auto STAGE = [&](int bufi, int kt) {
    gload16(gK + (size_t)kt * D_, &sK[bufi][(wid * 8) * 64]);
    gload16(gV + kt, &sV[bufi][(wid * 8) * 64]);
  };

  const int nt = 32 - 2 * pi;
  STAGE(0, 0);
  __syncthreads();
  int cur = 0;

  const int swz = ((ql & 7) << 3);  // row swizzle (same for ql and 32+ql)

  for (int t = 0; t < nt; ++t) {
    const int kt = t * 64;
    if (t + 1 < nt) STAGE(cur ^ 1, kt + 64);
    if (kt <= qw + 31) {
      const short* bK = &sK[cur][0];
      const short* bV = &sV[cur][0];
      // ---- preload all K fragments (8x ds_read_b128, pipelined) ----
      bf16x8 kf[8];
#pragma unroll
      for (int d = 0; d < 4; ++d) {
        const int co = ((d * 2 + h) << 3) ^ swz;
        kf[d]     = *(const bf16x8*)&bK[ql * 64 + co];
        kf[4 + d] = *(const bf16x8*)&bK[(32 + ql) * 64 + co];
      }
      // ---- QK^T swapped: p = P[key][q=qg] ----
      f32x16 p0, p1;
#pragma unroll
      for (int i = 0; i < 16; ++i) { p0[i] = 0.f; p1[i] = 0.f; }
      __builtin_amdgcn_s_setprio(1);
#pragma unroll
      for (int d = 0; d < 4; ++d) {
        p0 = __builtin_amdgcn_mfma_f32_32x32x16_bf16(kf[d], aQ[d], p0, 0, 0, 0);
        p1 = __builtin_amdgcn_mfma_f32_32x32x16_bf16(kf[4 + d], aQ[d], p1, 0, 0, 0);
      }
      __builtin_amdgcn_s_setprio(0);
      // ---- preload all V fragments (latency hides under softmax) ----
      bf16x8 vf[8];
#pragma unroll
      for (int m = 0; m < 4; ++m) {
        const int co = ((m * 2 + h) << 3) ^ swz;
        vf[m]     = *(const bf16x8*)&bV[ql * 64 + co];
        vf[4 + m] = *(const bf16x8*)&bV[(32 + ql) * 64 + co];
      }
      // ---- causal mask (diagonal tiles only) ----
      if (kt + 63 > qw) {
        const int qk = qg - kt;
#pragma unroll
        for (int i = 0; i < 16; ++i) {
          const int k0i = 8 * (i >> 2) + 4 * h + (i & 3);
          if (k0i > qk) p0[i] = -1e30f;
          if (k0i + 32 > qk) p1[i] = -1e30f;
        }
      }
      // ---- row max: tree reduce (depth 6) + shfl cross-half ----
      float tr[8];
#pragma unroll
      for (int i = 0; i < 8; ++i)
        tr[i] = fmaxf(fmaxf(p0[i], p0[i + 8]), fmaxf(p1[i], p1[i + 8]));
#pragma unroll
      for (int s = 4; s > 0; s >>= 1)
#pragma unroll
        for (int i = 0; i < s; ++i) tr[i] = fmaxf(tr[i], tr[i + s]);
      float mx = fmaxf(tr[0], __shfl_xor(tr[0], 32));
      // ---- defer-max rescale (wave-uniform skip) ----
      if (__any(mx > m_run + 8.f)) {
        const float mnew = fmaxf(m_run, mx);
        const float corr = exp2_hw(m_run - mnew);
        m_run = mnew;
        lsum *= corr;
#pragma unroll
        for (int i = 0; i < 16; ++i) { o0[i] *= corr; o1[i] *= corr; }
      }
      // ---- exp + sum tree ----
#pragma unroll
      for (int i = 0; i < 16; ++i) {
        p0[i] = exp2_hw(p0[i] - m_run);
        p1[i] = exp2_hw(p1[i] - m_run);
      }
      float sr[8];
#pragma unroll
      for (int i = 0; i < 8; ++i) sr[i] = (p0[i] + p0[i + 8]) + (p1[i] + p1[i + 8]);
#pragma unroll
      for (int s = 4; s > 0; s >>= 1)
#pragma unroll
        for (int i = 0; i < s; ++i) sr[i] += sr[i + s];
      lsum += sr[0] + __shfl_xor(sr[0], 32);
      // ---- pack P to bf16 pairs ----
      uint32_t cj[8], dj[8];
#pragma unroll
      for (int j = 0; j < 4; ++j) {
        cj[j]     = cvtpk(p0[4 * j], p0[4 * j + 1]);
        dj[j]     = cvtpk(p0[4 * j + 2], p0[4 * j + 3]);
        cj[4 + j] = cvtpk(p1[4 * j], p1[4 * j + 1]);
        dj[4 + j] = cvtpk(p1[4 * j + 2], p1[4 * j + 3]);
      }
      // ---- PV swapped: cross-half exchange via permlane32_swap builtin ----
      __builtin_amdgcn_s_setprio(1);
#pragma unroll
      for (int m = 0; m < 4; ++m) {
        uint32_t w0 = cj[2 * m], w2 = cj[2 * m + 1];
        plswap(w0, w2);
        uint32_t w1 = dj[2 * m], w3 = dj[2 * m + 1];
        plswap(w1, w3);
        union { uint32_t w[4]; bf16x8 v; } u;
        u.w[0] = w0; u.w[1] = w1; u.w[2] = w2; u.w[3] = w3;
        o0 = __builtin_amdgcn_mfma_f32_32x32x16_bf16(vf[m], u.v, o0, 0, 0, 0);
        o1 = __builtin_amdgcn_mfma_f32_32x32x16_bf16(vf[4 + m], u.v, o1, 0, 0, 0);
      }
      __builtin_amdgcn_s_setprio(0);
    }
    __syncthreads();
    cur ^= 1;
  }

  // ---- epilogue ----
  const float invl = 1.f / lsum;
  short* op = AO + rowbase + (size_t)qg * D_;
#pragma unroll
  for (int j = 0; j < 4; ++j) {
    s16x4 w0, w1;
#pragma unroll
    for (int r = 0; r < 4; ++r) {
      w0[r] = f2bf(o0[4 * j + r] * invl);
      w1[r] = f2bf(o1[4 * j + r] * invl);
    }
    *(s16x4*)(op + 8 * j + 4 * h) = w0;
    *(s16x4*)(op + 32 + 8 * j + 4 * h) = w1;
  }
}

// ---------------- launch -------------------------------------------------------
extern "C" void kernel_launch(void* const* d_in, const int* in_sizes, int n_in,
                              void* d_out, int out_size, void* d_ws, size_t ws_size,
                              hipStream_t stream) {
  (void)in_sizes; (void)n_in; (void)out_size; (void)ws_size;
  const float* q  = (const float*)d_in[0];
  const float* k  = (const float*)d_in[1];
  const float* v  = (const float*)d_in[2];
  const float* Wq = (const float*)d_in[4];
  const float* bq = (const float*)d_in[5];
  const float* Wk = (const float*)d_in[6];
  const float* bk = (const float*)d_in[7];
  const float* Wv = (const float*)d_in[8];
  const float* bv = (const float*)d_in[9];
  const float* Wo = (const float*)d_in[10];
  const float* bo = (const float*)d_in[11];

  char* ws = (char*)d_ws;
  const size_t MB = 1ull << 20;
  short* wqb = (short*)(ws + 0 * MB);
  short* wkb = (short*)(ws + 2 * MB);
  short* wvb = (short*)(ws + 4 * MB);
  short* wob = (short*)(ws + 6 * MB);
  short* Qf  = (short*)(ws + 8 * MB);
  short* Kf  = (short*)(ws + 24 * MB);
  short* Vtb = (short*)(ws + 40 * MB);  // transposed V: [(b*1024+n)][s]
  short* xq  = (short*)(ws + 56 * MB);
  short* xk  = (short*)(ws + 72 * MB);
  short* xv  = (short*)(ws + 88 * MB);
  short* AO  = xq;

  // fused conversions: {q,k,v} (BSD/8 = 2^20 groups each), 4 weights (2^17 each)
  cvt3<20><<<2048, 256, 0, stream>>>(q, k, v, v, xq, xk, xv, xv, 3);
  cvt3<17><<<1024, 256, 0, stream>>>(Wq, Wk, Wv, Wo, wqb, wkb, wvb, wob, 4);

  dim3 gg(M_ / 128, D_ / 128);
  // Q projection folds 1/sqrt(DK) * log2(e) so softmax runs in base-2
  gemm_bt<0><<<gg, 256, 0, stream>>>(xq, wqb, bq, Qf, D_, D_, 0.125f * 1.4426950408889634f);
  gemm_bt<0><<<gg, 256, 0, stream>>>(xk, wkb, bk, Kf, D_, D_, 1.0f);
  gemm_bt<2><<<gg, 256, 0, stream>>>(xv, wvb, bv, Vtb, D_, D_, 1.0f);

  attn_fwd<<<dim3(512), 512, 0, stream>>>(Qf, Kf, Vtb, AO);

  gemm_bt<1><<<gg, 256, 0, stream>>>(AO, wob, bo, d_out, D_, D_, 1.0f);
}

// Round 7
// 213.933 us; speedup vs baseline: 1.0627x; 1.0627x over previous
//
#include <hip/hip_runtime.h>
#include <stdint.h>

typedef __attribute__((ext_vector_type(8))) short bf16x8;
typedef __attribute__((ext_vector_type(4))) short s16x4;
typedef __attribute__((ext_vector_type(4))) float f32x4;
typedef __attribute__((ext_vector_type(16))) float f32x16;
typedef __attribute__((ext_vector_type(2))) unsigned u32x2;

#define DEVI __device__ __forceinline__

constexpr int B_ = 4, S_ = 2048, D_ = 1024, H_ = 16, DK_ = 64;
constexpr int M_ = B_ * S_;  // 8192 rows total

DEVI short f2bf(float f) {
  union { float f; uint32_t u; } x; x.f = f;
  uint32_t r = x.u + 0x7fffu + ((x.u >> 16) & 1u);  // RNE
  return (short)(uint16_t)(r >> 16);
}
DEVI float exp2_hw(float x) {  // v_exp_f32 is 2^x
  float r; asm("v_exp_f32 %0, %1" : "=v"(r) : "v"(x)); return r;
}
DEVI uint32_t cvtpk(float lo, float hi) {  // [15:0]=bf16(lo), [31:16]=bf16(hi)
  uint32_t r; asm("v_cvt_pk_bf16_f32 %0, %1, %2" : "=v"(r) : "v"(lo), "v"(hi));
  return r;
}
// cross-half swap: a' = {a.lo, b.lo(partner)}, b' = {a.hi(partner), b.hi}
#if __has_builtin(__builtin_amdgcn_permlane32_swap)
DEVI void plswap(uint32_t& a, uint32_t& b) {
  u32x2 r = __builtin_amdgcn_permlane32_swap(a, b, false, false);
  a = r[0]; b = r[1];
}
#else
DEVI void plswap(uint32_t& a, uint32_t& b) {
  const int h = (threadIdx.x & 63) >> 5;
  const uint32_t pa = (uint32_t)__shfl_xor((int)a, 32);
  const uint32_t pb = (uint32_t)__shfl_xor((int)b, 32);
  const uint32_t na = h ? pb : a;
  const uint32_t nb = h ? b : pa;
  a = na; b = nb;
}
#endif
DEVI void gload16(const short* g, short* l) {
  __builtin_amdgcn_global_load_lds((const __attribute__((address_space(1))) uint32_t*)g,
                                   (__attribute__((address_space(3))) uint32_t*)l, 16, 0, 0);
}

// ---------------- fp32 -> bf16 conversion, up to 4 same-size tensors ----------
template <int LOG2G>
__global__ __launch_bounds__(256) void cvt3(const float* __restrict__ s0,
                                            const float* __restrict__ s1,
                                            const float* __restrict__ s2,
                                            const float* __restrict__ s3,
                                            short* __restrict__ d0,
                                            short* __restrict__ d1,
                                            short* __restrict__ d2,
                                            short* __restrict__ d3,
                                            int narr) {
  const int stride = gridDim.x * blockDim.x;
  const int total = narr << LOG2G;
  for (int g = blockIdx.x * blockDim.x + threadIdx.x; g < total; g += stride) {
    const int a = g >> LOG2G;
    const size_t off = (size_t)(g & ((1 << LOG2G) - 1)) * 8;
    const float* src = (a == 0) ? s0 : (a == 1) ? s1 : (a == 2) ? s2 : s3;
    short* dst = (a == 0) ? d0 : (a == 1) ? d1 : (a == 2) ? d2 : d3;
    const f32x4 x = *(const f32x4*)(src + off);
    const f32x4 y = *(const f32x4*)(src + off + 4);
    bf16x8 o;
#pragma unroll
    for (int e = 0; e < 4; ++e) { o[e] = f2bf(x[e]); o[e + 4] = f2bf(y[e]); }
    *(bf16x8*)(dst + off) = o;
  }
}

// ---------------- bf16 GEMM: C[m,n] = (sum_k A[m,k]*W[n,k] + bias)*scale ------
// 128x128 tile, BK=32, 4 waves, 16x16x32 MFMA. 2-phase dbuf + XOR chunk swizzle.
// MODE 0: bf16 row-major out. MODE 1: f32 row-major out.
// MODE 2: bf16 out transposed into Vt[(b*1024+n)][s] (s = m % 2048), rows S_.
template <int MODE>
__global__ __launch_bounds__(256) void gemm_bt(const short* __restrict__ A,
                                               const short* __restrict__ Bw,
                                               const float* __restrict__ bias,
                                               void* __restrict__ Cout,
                                               int Kdim, int Ndim, float scale) {
  __shared__ short sA[2][128 * 32];
  __shared__ short sB[2][128 * 32];
  const int tid = threadIdx.x;
  const int wid = tid >> 6, lane = tid & 63;
  const int m0 = blockIdx.x * 128, n0 = blockIdx.y * 128;
  const int wm = wid >> 1, wn = wid & 1;

  f32x4 acc[4][4];
#pragma unroll
  for (int i = 0; i < 4; ++i)
#pragma unroll
    for (int j = 0; j < 4; ++j) acc[i][j] = (f32x4){0.f, 0.f, 0.f, 0.f};

  const int srow = wid * 32 + (lane >> 2);
  const int swzs = (srow & 3) ^ ((srow >> 2) & 3);
  const int scol = ((lane & 3) ^ swzs) * 8;
  const short* gA = A + (size_t)(m0 + srow) * Kdim + scol;
  const short* gB = Bw + (size_t)(n0 + srow) * Kdim + scol;

  auto STAGE = [&](int bi, int kt) {
    short* la = &sA[bi][(wid * 32) * 32];
    short* lb = &sB[bi][(wid * 32) * 32];
    gload16(gA + kt, la);
    gload16(gA + (size_t)16 * Kdim + kt, la + 16 * 32);
    gload16(gB + kt, lb);
    gload16(gB + (size_t)16 * Kdim + kt, lb + 16 * 32);
  };

  STAGE(0, 0);
  __syncthreads();
  int cur = 0;

  const int swzf = (lane & 3) ^ ((lane >> 2) & 3);
  const int cofs = (((lane >> 4) ^ swzf) << 3);

  for (int kt = 0; kt < Kdim; kt += 32) {
    if (kt + 32 < Kdim) STAGE(cur ^ 1, kt + 32);
    bf16x8 af[4], bfr[4];
#pragma unroll
    for (int mf = 0; mf < 4; ++mf)
      af[mf] = *(const bf16x8*)&sA[cur][(wm * 64 + mf * 16 + (lane & 15)) * 32 + cofs];
#pragma unroll
    for (int nf = 0; nf < 4; ++nf)
      bfr[nf] = *(const bf16x8*)&sB[cur][(wn * 64 + nf * 16 + (lane & 15)) * 32 + cofs];
#pragma unroll
    for (int mf = 0; mf < 4; ++mf)
#pragma unroll
      for (int nf = 0; nf < 4; ++nf)
        acc[mf][nf] = __builtin_amdgcn_mfma_f32_16x16x32_bf16(af[mf], bfr[nf], acc[mf][nf], 0, 0, 0);
    __syncthreads();
    cur ^= 1;
  }

#pragma unroll
  for (int mf = 0; mf < 4; ++mf) {
#pragma unroll
    for (int nf = 0; nf < 4; ++nf) {
      const int n = n0 + wn * 64 + nf * 16 + (lane & 15);
      const float bi = bias[n];
      if (MODE == 2) {
        const int m_base = m0 + wm * 64 + mf * 16 + ((lane >> 4) * 4);
        const int b = m_base >> 11, s0 = m_base & 2047;
        s16x4 pk;
#pragma unroll
        for (int r = 0; r < 4; ++r) pk[r] = f2bf(acc[mf][nf][r] + bi);
        *(s16x4*)((short*)Cout + ((size_t)(b * 1024 + n)) * 2048 + s0) = pk;
      } else {
#pragma unroll
        for (int r = 0; r < 4; ++r) {
          const int m = m0 + wm * 64 + mf * 16 + ((lane >> 4) * 4) + r;
          const float vv = (acc[mf][nf][r] + bi) * scale;
          if (MODE == 0)
            ((short*)Cout)[(size_t)m * Ndim + n] = f2bf(vv);
          else
            ((float*)Cout)[(size_t)m * Ndim + n] = vv;
        }
      }
    }
  }
}

// ---------------- causal flash attention (split-K pairs) ----------------------
// Block = one 128-q-row panel, 8 waves. Waves w and w+4 own the SAME 32 q-rows
// with disjoint K-tile ranges [0,ha) / [ha,2ha), ha = panel+1  => every wave
// computes every iteration. Two tile streams staged per iter (64KB LDS, dbuf).
// Partials merged at the end via LDS (flash-decoding style). R4-proven inner
// body: 32x32x16 swapped MFMA, in-loop frag loads, in-register softmax,
// per-lane defer-max, permlane32_swap P-exchange, setprio on MFMA clusters.
__global__ __launch_bounds__(512, 4) void attn_fwd(const short* __restrict__ Qf,
                                                   const short* __restrict__ Kf,
                                                   const short* __restrict__ Vt,
                                                   short* __restrict__ AO) {
  __shared__ short sK[2][2][64 * 64];   // [buf][grp][key][d], swizzled chunks
  __shared__ short sV[2][2][64 * 64];   // [buf][grp][d][key], swizzled chunks

  const int tid = threadIdx.x, wid = tid >> 6, lane = tid & 63;
  const int h = lane >> 5, ql = lane & 31;
  const int grp = wid >> 2, ww = wid & 3;
  // bijective XCD swizzle (1024 % 8 == 0): 8 consecutive bh per XCD,
  // panels issued heavy-first within each bh.
  const int cpx = gridDim.x >> 3;
  const int wg = ((int)blockIdx.x & 7) * cpx + ((int)blockIdx.x >> 3);
  const int bh = wg >> 4;
  const int panel = 15 - (wg & 15);
  const int b = bh >> 4, hd = bh & 15;
  const int qw = panel * 128 + ww * 32;
  const int qg = qw + ql;
  const size_t rowbase = (size_t)b * S_ * D_ + (size_t)hd * DK_;
  const size_t vbase = (size_t)bh * 64 * S_;
  const int ha = panel + 1;     // tiles per group
  const int ktb = grp * ha;     // this group's first tile index

  // Q fragments: B[q=qg][d = dstep*16 + h*8 .. +8]  (scaled by 0.125*log2e)
  bf16x8 aQ[4];
  {
    const short* qp = Qf + rowbase + (size_t)qg * D_ + h * 8;
#pragma unroll
    for (int d = 0; d < 4; ++d) aQ[d] = *(const bf16x8*)(qp + d * 16);
  }

  f32x16 o0, o1;  // O[d][q=qg] partial for this K-range
#pragma unroll
  for (int i = 0; i < 16; ++i) { o0[i] = 0.f; o1[i] = 0.f; }
  float m_run = -1e30f, lsum = 0.f;

  // staging: wave stages rows [ww*16, ww*16+16) of its group's K and V tiles.
  // LDS[r][c] = G[r][c ^ (r&7)] via pre-swizzled per-lane source chunk.
  const int srow8 = lane >> 3;
  const int schunk = ((lane & 7) ^ srow8) * 8;
  const short* gK = Kf + rowbase + (size_t)(ww * 16 + srow8) * D_ + schunk;
  const short* gV = Vt + vbase + (size_t)(ww * 16 + srow8) * S_ + schunk;

  auto STAGE = [&](int bufi, int t) {
    const int kt = (ktb + t) * 64;
    short* dk = &sK[bufi][grp][(ww * 16) * 64];
    short* dv = &sV[bufi][grp][(ww * 16) * 64];
    gload16(gK + (size_t)kt * D_, dk);
    gload16(gK + (size_t)(kt + 8) * D_, dk + 8 * 64);
    gload16(gV + kt, dv);
    gload16(gV + (size_t)8 * S_ + kt, dv + 8 * 64);
  };

  STAGE(0, 0);
  __syncthreads();
  int cur = 0;

  const int swz = ((ql & 7) << 3);  // row swizzle (same for ql and 32+ql)

  for (int t = 0; t < ha; ++t) {
    const int kt = (ktb + t) * 64;
    if (t + 1 < ha) STAGE(cur ^ 1, t + 1);
    if (kt <= qw + 31) {  // group A: always true; group B: skips past-diag
      const short* bK = &sK[cur][grp][0];
      const short* bV = &sV[cur][grp][0];
      // ---- QK^T swapped: p = P[key][q=qg] ----
      f32x16 p0, p1;
#pragma unroll
      for (int i = 0; i < 16; ++i) { p0[i] = 0.f; p1[i] = 0.f; }
      __builtin_amdgcn_s_setprio(1);
#pragma unroll
      for (int d = 0; d < 4; ++d) {
        const int co = ((d * 2 + h) << 3) ^ swz;
        bf16x8 k0 = *(const bf16x8*)&bK[ql * 64 + co];
        bf16x8 k1 = *(const bf16x8*)&bK[(32 + ql) * 64 + co];
        p0 = __builtin_amdgcn_mfma_f32_32x32x16_bf16(k0, aQ[d], p0, 0, 0, 0);
        p1 = __builtin_amdgcn_mfma_f32_32x32x16_bf16(k1, aQ[d], p1, 0, 0, 0);
      }
      __builtin_amdgcn_s_setprio(0);
      // ---- causal mask (diagonal tiles only) ----
      if (kt + 63 > qw) {
        const int qk = qg - kt;
#pragma unroll
        for (int i = 0; i < 16; ++i) {
          const int k0i = 8 * (i >> 2) + 4 * h + (i & 3);
          if (k0i > qk) p0[i] = -1e30f;
          if (k0i + 32 > qk) p1[i] = -1e30f;
        }
      }
      // ---- online softmax (base-2), defer-max ----
      float mx = fmaxf(p0[0], p1[0]);
#pragma unroll
      for (int i = 1; i < 16; ++i) mx = fmaxf(mx, fmaxf(p0[i], p1[i]));
      mx = fmaxf(mx, __shfl_xor(mx, 32));
      if (mx > m_run + 8.f) {
        const float corr = exp2_hw(m_run - mx);
        m_run = mx;
        lsum *= corr;
#pragma unroll
        for (int i = 0; i < 16; ++i) { o0[i] *= corr; o1[i] *= corr; }
      }
      float rs = 0.f;
#pragma unroll
      for (int i = 0; i < 16; ++i) {
        p0[i] = exp2_hw(p0[i] - m_run); rs += p0[i];
        p1[i] = exp2_hw(p1[i] - m_run); rs += p1[i];
      }
      rs += __shfl_xor(rs, 32);
      lsum += rs;
      // ---- pack P to bf16 pairs ----
      uint32_t cj[8], dj[8];
#pragma unroll
      for (int j = 0; j < 4; ++j) {
        cj[j]     = cvtpk(p0[4 * j], p0[4 * j + 1]);
        dj[j]     = cvtpk(p0[4 * j + 2], p0[4 * j + 3]);
        cj[4 + j] = cvtpk(p1[4 * j], p1[4 * j + 1]);
        dj[4 + j] = cvtpk(p1[4 * j + 2], p1[4 * j + 3]);
      }
      // ---- PV swapped: cross-half exchange via permlane32_swap ----
      __builtin_amdgcn_s_setprio(1);
#pragma unroll
      for (int m = 0; m < 4; ++m) {
        uint32_t w0 = cj[2 * m], w2 = cj[2 * m + 1];
        plswap(w0, w2);
        uint32_t w1 = dj[2 * m], w3 = dj[2 * m + 1];
        plswap(w1, w3);
        union { uint32_t w[4]; bf16x8 v; } u;
        u.w[0] = w0; u.w[1] = w1; u.w[2] = w2; u.w[3] = w3;
        const int co = ((m * 2 + h) << 3) ^ swz;
        bf16x8 v0 = *(const bf16x8*)&bV[ql * 64 + co];
        bf16x8 v1 = *(const bf16x8*)&bV[(32 + ql) * 64 + co];
        o0 = __builtin_amdgcn_mfma_f32_32x32x16_bf16(v0, u.v, o0, 0, 0, 0);
        o1 = __builtin_amdgcn_mfma_f32_32x32x16_bf16(v1, u.v, o1, 0, 0, 0);
      }
      __builtin_amdgcn_s_setprio(0);
    }
    __syncthreads();  // drains vmcnt(0): tile t+1 landed; all done reading cur
    cur ^= 1;
  }

  // ---- split-K merge: group B publishes partials; group A combines+writes ----
  float* ml = (float*)&sK[0][0][0];  // [pair][2][lane]   (2 KB)
  float* ov = (float*)&sV[0][0][0];  // [pair][32][lane]  (32 KB)
  if (grp == 1) {
    ml[(ww * 2 + 0) * 64 + lane] = m_run;
    ml[(ww * 2 + 1) * 64 + lane] = lsum;
#pragma unroll
    for (int r = 0; r < 16; ++r) {
      ov[(ww * 32 + r) * 64 + lane] = o0[r];
      ov[(ww * 32 + 16 + r) * 64 + lane] = o1[r];
    }
  }
  __syncthreads();
  if (grp == 0) {
    const float mb = ml[(ww * 2 + 0) * 64 + lane];
    const float lb = ml[(ww * 2 + 1) * 64 + lane];
    const float mm = fmaxf(m_run, mb);
    const float ca = exp2_hw(m_run - mm);
    const float cb = exp2_hw(mb - mm);
    const float invl = 1.f / (lsum * ca + lb * cb);
    short* op = AO + rowbase + (size_t)qg * D_;
#pragma unroll
    for (int j = 0; j < 4; ++j) {
      s16x4 w0, w1;
#pragma unroll
      for (int r = 0; r < 4; ++r) {
        const float b0 = ov[(ww * 32 + 4 * j + r) * 64 + lane];
        const float b1 = ov[(ww * 32 + 16 + 4 * j + r) * 64 + lane];
        w0[r] = f2bf((o0[4 * j + r] * ca + b0 * cb) * invl);
        w1[r] = f2bf((o1[4 * j + r] * ca + b1 * cb) * invl);
      }
      *(s16x4*)(op + 8 * j + 4 * h) = w0;
      *(s16x4*)(op + 32 + 8 * j + 4 * h) = w1;
    }
  }
}

// ---------------- launch -------------------------------------------------------
extern "C" void kernel_launch(void* const* d_in, const int* in_sizes, int n_in,
                              void* d_out, int out_size, void* d_ws, size_t ws_size,
                              hipStream_t stream) {
  (void)in_sizes; (void)n_in; (void)out_size; (void)ws_size;
  const float* q  = (const float*)d_in[0];
  const float* k  = (const float*)d_in[1];
  const float* v  = (const float*)d_in[2];
  const float* Wq = (const float*)d_in[4];
  const float* bq = (const float*)d_in[5];
  const float* Wk = (const float*)d_in[6];
  const float* bk = (const float*)d_in[7];
  const float* Wv = (const float*)d_in[8];
  const float* bv = (const float*)d_in[9];
  const float* Wo = (const float*)d_in[10];
  const float* bo = (const float*)d_in[11];

  char* ws = (char*)d_ws;
  const size_t MB = 1ull << 20;
  short* wqb = (short*)(ws + 0 * MB);
  short* wkb = (short*)(ws + 2 * MB);
  short* wvb = (short*)(ws + 4 * MB);
  short* wob = (short*)(ws + 6 * MB);
  short* Qf  = (short*)(ws + 8 * MB);
  short* Kf  = (short*)(ws + 24 * MB);
  short* Vtb = (short*)(ws + 40 * MB);  // transposed V: [(b*1024+n)][s]
  short* xq  = (short*)(ws + 56 * MB);
  short* xk  = (short*)(ws + 72 * MB);
  short* xv  = (short*)(ws + 88 * MB);
  short* AO  = xq;

  // fused conversions: {q,k,v} (BSD/8 = 2^20 groups each), 4 weights (2^17 each)
  cvt3<20><<<2048, 256, 0, stream>>>(q, k, v, v, xq, xk, xv, xv, 3);
  cvt3<17><<<1024, 256, 0, stream>>>(Wq, Wk, Wv, Wo, wqb, wkb, wvb, wob, 4);

  dim3 gg(M_ / 128, D_ / 128);
  // Q projection folds 1/sqrt(DK) * log2(e) so softmax runs in base-2
  gemm_bt<0><<<gg, 256, 0, stream>>>(xq, wqb, bq, Qf, D_, D_, 0.125f * 1.4426950408889634f);
  gemm_bt<0><<<gg, 256, 0, stream>>>(xk, wkb, bk, Kf, D_, D_, 1.0f);
  gemm_bt<2><<<gg, 256, 0, stream>>>(xv, wvb, bv, Vtb, D_, D_, 1.0f);

  attn_fwd<<<dim3(1024), 512, 0, stream>>>(Qf, Kf, Vtb, AO);

  gemm_bt<1><<<gg, 256, 0, stream>>>(AO, wob, bo, d_out, D_, D_, 1.0f);
}

// Round 8
// 200.131 us; speedup vs baseline: 1.1360x; 1.0690x over previous
//
#include <hip/hip_runtime.h>
#include <stdint.h>

typedef __attribute__((ext_vector_type(8))) short bf16x8;
typedef __attribute__((ext_vector_type(4))) short s16x4;
typedef __attribute__((ext_vector_type(4))) float f32x4;
typedef __attribute__((ext_vector_type(16))) float f32x16;
typedef __attribute__((ext_vector_type(2))) unsigned u32x2;

#define DEVI __device__ __forceinline__

constexpr int B_ = 4, S_ = 2048, D_ = 1024, H_ = 16, DK_ = 64;
constexpr int M_ = B_ * S_;  // 8192 rows total

DEVI short f2bf(float f) {
  union { float f; uint32_t u; } x; x.f = f;
  uint32_t r = x.u + 0x7fffu + ((x.u >> 16) & 1u);  // RNE
  return (short)(uint16_t)(r >> 16);
}
DEVI float exp2_hw(float x) {  // v_exp_f32 is 2^x
  float r; asm("v_exp_f32 %0, %1" : "=v"(r) : "v"(x)); return r;
}
DEVI uint32_t cvtpk(float lo, float hi) {  // [15:0]=bf16(lo), [31:16]=bf16(hi)
  uint32_t r; asm("v_cvt_pk_bf16_f32 %0, %1, %2" : "=v"(r) : "v"(lo), "v"(hi));
  return r;
}
// cross-half swap: a' = {a.lo, b.lo(partner)}, b' = {a.hi(partner), b.hi}
#if __has_builtin(__builtin_amdgcn_permlane32_swap)
DEVI void plswap(uint32_t& a, uint32_t& b) {
  u32x2 r = __builtin_amdgcn_permlane32_swap(a, b, false, false);
  a = r[0]; b = r[1];
}
#else
DEVI void plswap(uint32_t& a, uint32_t& b) {
  const int h = (threadIdx.x & 63) >> 5;
  const uint32_t pa = (uint32_t)__shfl_xor((int)a, 32);
  const uint32_t pb = (uint32_t)__shfl_xor((int)b, 32);
  const uint32_t na = h ? pb : a;
  const uint32_t nb = h ? b : pa;
  a = na; b = nb;
}
#endif
DEVI void gload16(const short* g, short* l) {
  __builtin_amdgcn_global_load_lds((const __attribute__((address_space(1))) uint32_t*)g,
                                   (__attribute__((address_space(3))) uint32_t*)l, 16, 0, 0);
}

// ---------------- fp32 -> bf16 conversion, up to 4 same-size tensors ----------
template <int LOG2G>
__global__ __launch_bounds__(256) void cvt3(const float* __restrict__ s0,
                                            const float* __restrict__ s1,
                                            const float* __restrict__ s2,
                                            const float* __restrict__ s3,
                                            short* __restrict__ d0,
                                            short* __restrict__ d1,
                                            short* __restrict__ d2,
                                            short* __restrict__ d3,
                                            int narr) {
  const int stride = gridDim.x * blockDim.x;
  const int total = narr << LOG2G;
  for (int g = blockIdx.x * blockDim.x + threadIdx.x; g < total; g += stride) {
    const int a = g >> LOG2G;
    const size_t off = (size_t)(g & ((1 << LOG2G) - 1)) * 8;
    const float* src = (a == 0) ? s0 : (a == 1) ? s1 : (a == 2) ? s2 : s3;
    short* dst = (a == 0) ? d0 : (a == 1) ? d1 : (a == 2) ? d2 : d3;
    const f32x4 x = *(const f32x4*)(src + off);
    const f32x4 y = *(const f32x4*)(src + off + 4);
    bf16x8 o;
#pragma unroll
    for (int e = 0; e < 4; ++e) { o[e] = f2bf(x[e]); o[e + 4] = f2bf(y[e]); }
    *(bf16x8*)(dst + off) = o;
  }
}

// ---------------- bf16 GEMM: C[m,n] = (sum_k A[m,k]*W[n,k] + bias)*scale ------
// 128x128 tile, BK=32, EIGHT waves (4M x 2N, 32x64 per wave), 16x16x32 MFMA.
// 2-phase dbuf + XOR chunk swizzle. 2 blocks/CU -> 4 waves/SIMD.
// MODE 0: bf16 row-major out. MODE 1: f32 row-major out.
// MODE 2: bf16 out transposed into Vt[(b*1024+n)][s] (s = m % 2048), rows S_.
template <int MODE>
__global__ __launch_bounds__(512, 4) void gemm_bt(const short* __restrict__ A,
                                                  const short* __restrict__ Bw,
                                                  const float* __restrict__ bias,
                                                  void* __restrict__ Cout,
                                                  int Kdim, int Ndim, float scale) {
  __shared__ short sA[2][128 * 32];
  __shared__ short sB[2][128 * 32];
  const int tid = threadIdx.x;
  const int wid = tid >> 6, lane = tid & 63;
  const int m0 = blockIdx.x * 128, n0 = blockIdx.y * 128;
  const int wm = wid >> 1, wn = wid & 1;  // 4 x 2 wave grid, 32x64 per wave

  f32x4 acc[2][4];
#pragma unroll
  for (int i = 0; i < 2; ++i)
#pragma unroll
    for (int j = 0; j < 4; ++j) acc[i][j] = (f32x4){0.f, 0.f, 0.f, 0.f};

  // staging: wave covers rows [wid*16, wid*16+16), 1 issue per operand.
  // LDS[r][c] = G[r][c ^ swz(r)], swz(r) = (r&3)^((r>>2)&3)
  const int srow = wid * 16 + (lane >> 2);
  const int swzs = (srow & 3) ^ ((srow >> 2) & 3);
  const int scol = ((lane & 3) ^ swzs) * 8;
  const short* gA = A + (size_t)(m0 + srow) * Kdim + scol;
  const short* gB = Bw + (size_t)(n0 + srow) * Kdim + scol;

  auto STAGE = [&](int bi, int kt) {
    gload16(gA + kt, &sA[bi][(wid * 16) * 32]);
    gload16(gB + kt, &sB[bi][(wid * 16) * 32]);
  };

  STAGE(0, 0);
  __syncthreads();
  int cur = 0;

  // frag-read swizzle: row = base16 + (lane&15) -> swz = (lane&3)^((lane>>2)&3)
  const int swzf = (lane & 3) ^ ((lane >> 2) & 3);
  const int cofs = (((lane >> 4) ^ swzf) << 3);

  for (int kt = 0; kt < Kdim; kt += 32) {
    if (kt + 32 < Kdim) STAGE(cur ^ 1, kt + 32);
    bf16x8 af[2], bfr[4];
#pragma unroll
    for (int mf = 0; mf < 2; ++mf)
      af[mf] = *(const bf16x8*)&sA[cur][(wm * 32 + mf * 16 + (lane & 15)) * 32 + cofs];
#pragma unroll
    for (int nf = 0; nf < 4; ++nf)
      bfr[nf] = *(const bf16x8*)&sB[cur][(wn * 64 + nf * 16 + (lane & 15)) * 32 + cofs];
#pragma unroll
    for (int mf = 0; mf < 2; ++mf)
#pragma unroll
      for (int nf = 0; nf < 4; ++nf)
        acc[mf][nf] = __builtin_amdgcn_mfma_f32_16x16x32_bf16(af[mf], bfr[nf], acc[mf][nf], 0, 0, 0);
    __syncthreads();  // drains vmcnt(0)+lgkmcnt(0): next tile landed, reads done
    cur ^= 1;
  }

#pragma unroll
  for (int mf = 0; mf < 2; ++mf) {
#pragma unroll
    for (int nf = 0; nf < 4; ++nf) {
      const int n = n0 + wn * 64 + nf * 16 + (lane & 15);
      const float bi = bias[n];
      if (MODE == 2) {
        const int m_base = m0 + wm * 32 + mf * 16 + ((lane >> 4) * 4);
        const int b = m_base >> 11, s0 = m_base & 2047;
        s16x4 pk;
#pragma unroll
        for (int r = 0; r < 4; ++r) pk[r] = f2bf(acc[mf][nf][r] + bi);
        *(s16x4*)((short*)Cout + ((size_t)(b * 1024 + n)) * 2048 + s0) = pk;
      } else {
#pragma unroll
        for (int r = 0; r < 4; ++r) {
          const int m = m0 + wm * 32 + mf * 16 + ((lane >> 4) * 4) + r;
          const float vv = (acc[mf][nf][r] + bi) * scale;
          if (MODE == 0)
            ((short*)Cout)[(size_t)m * Ndim + n] = f2bf(vv);
          else
            ((float*)Cout)[(size_t)m * Ndim + n] = vv;
        }
      }
    }
  }
}

// ---------------- causal flash attention (R4 structure) ------------------------
// 8 waves x 32 q-rows, causal load-pairing: waves 0-3 -> panel (15-pi),
// waves 4-7 -> panel pi => uniform 34 wave-tile budget, K/V staged ONCE for all
// 8 waves (32KB LDS). 32x32x16 MFMA swapped operands, in-loop frag loads,
// tree reductions, per-lane defer-max, permlane32_swap P-exchange, setprio.
__global__ __launch_bounds__(512, 4) void attn_fwd(const short* __restrict__ Qf,
                                                   const short* __restrict__ Kf,
                                                   const short* __restrict__ Vt,
                                                   short* __restrict__ AO) {
  __shared__ short sK[2][64 * 64];   // [key][d], swizzled chunks
  __shared__ short sV[2][64 * 64];   // [d][key], swizzled chunks

  const int tid = threadIdx.x, wid = tid >> 6, lane = tid & 63;
  const int h = lane >> 5, ql = lane & 31;
  const int cpx = gridDim.x >> 3;
  const int wg = ((int)blockIdx.x & 7) * cpx + ((int)blockIdx.x >> 3);
  const int bh = wg >> 3;
  const int pi = wg & 7;
  const int b = bh >> 4, hd = bh & 15;
  const int panel = (wid < 4) ? (15 - pi) : pi;
  const int qw = panel * 128 + (wid & 3) * 32;
  const int qg = qw + ql;
  const size_t rowbase = (size_t)b * S_ * D_ + (size_t)hd * DK_;
  const size_t vbase = (size_t)bh * 64 * S_;

  bf16x8 aQ[4];
  {
    const short* qp = Qf + rowbase + (size_t)qg * D_ + h * 8;
#pragma unroll
    for (int d = 0; d < 4; ++d) aQ[d] = *(const bf16x8*)(qp + d * 16);
  }

  f32x16 o0, o1;
#pragma unroll
  for (int i = 0; i < 16; ++i) { o0[i] = 0.f; o1[i] = 0.f; }
  float m_run = -1e30f, lsum = 0.f;

  const int srow8 = lane >> 3;
  const int schunk = ((lane & 7) ^ srow8) * 8;
  const short* gK = Kf + rowbase + (size_t)(wid * 8 + srow8) * D_ + schunk;
  const short* gV = Vt + vbase + (size_t)(wid * 8 + srow8) * S_ + schunk;

  auto STAGE = [&](int bufi, int kt) {
    gload16(gK + (size_t)kt * D_, &sK[bufi][(wid * 8) * 64]);
    gload16(gV + kt, &sV[bufi][(wid * 8) * 64]);
  };

  const int nt = 32 - 2 * pi;
  STAGE(0, 0);
  __syncthreads();
  int cur = 0;

  const int swz = ((ql & 7) << 3);  // row swizzle (same for ql and 32+ql)

  for (int t = 0; t < nt; ++t) {
    const int kt = t * 64;
    if (t + 1 < nt) STAGE(cur ^ 1, kt + 64);
    if (kt <= qw + 31) {
      const short* bK = &sK[cur][0];
      const short* bV = &sV[cur][0];
      // ---- QK^T swapped: p = P[key][q=qg], in-loop frag loads ----
      f32x16 p0, p1;
#pragma unroll
      for (int i = 0; i < 16; ++i) { p0[i] = 0.f; p1[i] = 0.f; }
      __builtin_amdgcn_s_setprio(1);
#pragma unroll
      for (int d = 0; d < 4; ++d) {
        const int co = ((d * 2 + h) << 3) ^ swz;
        bf16x8 k0 = *(const bf16x8*)&bK[ql * 64 + co];
        bf16x8 k1 = *(const bf16x8*)&bK[(32 + ql) * 64 + co];
        p0 = __builtin_amdgcn_mfma_f32_32x32x16_bf16(k0, aQ[d], p0, 0, 0, 0);
        p1 = __builtin_amdgcn_mfma_f32_32x32x16_bf16(k1, aQ[d], p1, 0, 0, 0);
      }
      __builtin_amdgcn_s_setprio(0);
      // ---- causal mask (diagonal tiles only) ----
      if (kt + 63 > qw) {
        const int qk = qg - kt;
#pragma unroll
        for (int i = 0; i < 16; ++i) {
          const int k0i = 8 * (i >> 2) + 4 * h + (i & 3);
          if (k0i > qk) p0[i] = -1e30f;
          if (k0i + 32 > qk) p1[i] = -1e30f;
        }
      }
      // ---- row max: register tree (depth 5) + cross-half shfl ----
      float tr[8];
#pragma unroll
      for (int i = 0; i < 8; ++i)
        tr[i] = fmaxf(fmaxf(p0[i], p0[i + 8]), fmaxf(p1[i], p1[i + 8]));
#pragma unroll
      for (int s = 4; s > 0; s >>= 1)
#pragma unroll
        for (int i = 0; i < s; ++i) tr[i] = fmaxf(tr[i], tr[i + s]);
      float mx = fmaxf(tr[0], __shfl_xor(tr[0], 32));
      // ---- defer-max rescale ----
      if (mx > m_run + 8.f) {
        const float corr = exp2_hw(m_run - mx);
        m_run = mx;
        lsum *= corr;
#pragma unroll
        for (int i = 0; i < 16; ++i) { o0[i] *= corr; o1[i] *= corr; }
      }
      // ---- exp + sum tree ----
#pragma unroll
      for (int i = 0; i < 16; ++i) {
        p0[i] = exp2_hw(p0[i] - m_run);
        p1[i] = exp2_hw(p1[i] - m_run);
      }
      float sr[8];
#pragma unroll
      for (int i = 0; i < 8; ++i) sr[i] = (p0[i] + p0[i + 8]) + (p1[i] + p1[i + 8]);
#pragma unroll
      for (int s = 4; s > 0; s >>= 1)
#pragma unroll
        for (int i = 0; i < s; ++i) sr[i] += sr[i + s];
      lsum += sr[0] + __shfl_xor(sr[0], 32);
      // ---- pack P to bf16 pairs ----
      uint32_t cj[8], dj[8];
#pragma unroll
      for (int j = 0; j < 4; ++j) {
        cj[j]     = cvtpk(p0[4 * j], p0[4 * j + 1]);
        dj[j]     = cvtpk(p0[4 * j + 2], p0[4 * j + 3]);
        cj[4 + j] = cvtpk(p1[4 * j], p1[4 * j + 1]);
        dj[4 + j] = cvtpk(p1[4 * j + 2], p1[4 * j + 3]);
      }
      // ---- PV swapped: cross-half exchange via permlane32_swap, in-loop V ----
      __builtin_amdgcn_s_setprio(1);
#pragma unroll
      for (int m = 0; m < 4; ++m) {
        uint32_t w0 = cj[2 * m], w2 = cj[2 * m + 1];
        plswap(w0, w2);
        uint32_t w1 = dj[2 * m], w3 = dj[2 * m + 1];
        plswap(w1, w3);
        union { uint32_t w[4]; bf16x8 v; } u;
        u.w[0] = w0; u.w[1] = w1; u.w[2] = w2; u.w[3] = w3;
        const int co = ((m * 2 + h) << 3) ^ swz;
        bf16x8 v0 = *(const bf16x8*)&bV[ql * 64 + co];
        bf16x8 v1 = *(const bf16x8*)&bV[(32 + ql) * 64 + co];
        o0 = __builtin_amdgcn_mfma_f32_32x32x16_bf16(v0, u.v, o0, 0, 0, 0);
        o1 = __builtin_amdgcn_mfma_f32_32x32x16_bf16(v1, u.v, o1, 0, 0, 0);
      }
      __builtin_amdgcn_s_setprio(0);
    }
    __syncthreads();  // drains vmcnt(0): tile t+1 landed; all done reading cur
    cur ^= 1;
  }

  // ---- epilogue ----
  const float invl = 1.f / lsum;
  short* op = AO + rowbase + (size_t)qg * D_;
#pragma unroll
  for (int j = 0; j < 4; ++j) {
    s16x4 w0, w1;
#pragma unroll
    for (int r = 0; r < 4; ++r) {
      w0[r] = f2bf(o0[4 * j + r] * invl);
      w1[r] = f2bf(o1[4 * j + r] * invl);
    }
    *(s16x4*)(op + 8 * j + 4 * h) = w0;
    *(s16x4*)(op + 32 + 8 * j + 4 * h) = w1;
  }
}

// ---------------- launch -------------------------------------------------------
extern "C" void kernel_launch(void* const* d_in, const int* in_sizes, int n_in,
                              void* d_out, int out_size, void* d_ws, size_t ws_size,
                              hipStream_t stream) {
  (void)in_sizes; (void)n_in; (void)out_size; (void)ws_size;
  const float* q  = (const float*)d_in[0];
  const float* k  = (const float*)d_in[1];
  const float* v  = (const float*)d_in[2];
  const float* Wq = (const float*)d_in[4];
  const float* bq = (const float*)d_in[5];
  const float* Wk = (const float*)d_in[6];
  const float* bk = (const float*)d_in[7];
  const float* Wv = (const float*)d_in[8];
  const float* bv = (const float*)d_in[9];
  const float* Wo = (const float*)d_in[10];
  const float* bo = (const float*)d_in[11];

  char* ws = (char*)d_ws;
  const size_t MB = 1ull << 20;
  short* wqb = (short*)(ws + 0 * MB);
  short* wkb = (short*)(ws + 2 * MB);
  short* wvb = (short*)(ws + 4 * MB);
  short* wob = (short*)(ws + 6 * MB);
  short* Qf  = (short*)(ws + 8 * MB);
  short* Kf  = (short*)(ws + 24 * MB);
  short* Vtb = (short*)(ws + 40 * MB);  // transposed V: [(b*1024+n)][s]
  short* xq  = (short*)(ws + 56 * MB);
  short* xk  = (short*)(ws + 72 * MB);
  short* xv  = (short*)(ws + 88 * MB);
  short* AO  = xq;

  // fused conversions: {q,k,v} (BSD/8 = 2^20 groups each), 4 weights (2^17 each)
  cvt3<20><<<2048, 256, 0, stream>>>(q, k, v, v, xq, xk, xv, xv, 3);
  cvt3<17><<<1024, 256, 0, stream>>>(Wq, Wk, Wv, Wo, wqb, wkb, wvb, wob, 4);

  dim3 gg(M_ / 128, D_ / 128);
  // Q projection folds 1/sqrt(DK) * log2(e) so softmax runs in base-2
  gemm_bt<0><<<gg, 512, 0, stream>>>(xq, wqb, bq, Qf, D_, D_, 0.125f * 1.4426950408889634f);
  gemm_bt<0><<<gg, 512, 0, stream>>>(xk, wkb, bk, Kf, D_, D_, 1.0f);
  gemm_bt<2><<<gg, 512, 0, stream>>>(xv, wvb, bv, Vtb, D_, D_, 1.0f);

  attn_fwd<<<dim3(512), 512, 0, stream>>>(Qf, Kf, Vtb, AO);

  gemm_bt<1><<<gg, 512, 0, stream>>>(AO, wob, bo, d_out, D_, D_, 1.0f);
}

// Round 9
// 189.014 us; speedup vs baseline: 1.2028x; 1.0588x over previous
//
#include <hip/hip_runtime.h>
#include <stdint.h>

typedef __attribute__((ext_vector_type(8))) short bf16x8;
typedef __attribute__((ext_vector_type(4))) short s16x4;
typedef __attribute__((ext_vector_type(4))) float f32x4;
typedef __attribute__((ext_vector_type(16))) float f32x16;
typedef __attribute__((ext_vector_type(2))) unsigned u32x2;

#define DEVI __device__ __forceinline__

constexpr int B_ = 4, S_ = 2048, D_ = 1024, H_ = 16, DK_ = 64;
constexpr int M_ = B_ * S_;  // 8192 rows total

DEVI short f2bf(float f) {
  union { float f; uint32_t u; } x; x.f = f;
  uint32_t r = x.u + 0x7fffu + ((x.u >> 16) & 1u);  // RNE
  return (short)(uint16_t)(r >> 16);
}
DEVI float exp2_hw(float x) {  // v_exp_f32 is 2^x
  float r; asm("v_exp_f32 %0, %1" : "=v"(r) : "v"(x)); return r;
}
DEVI uint32_t cvtpk(float lo, float hi) {  // [15:0]=bf16(lo), [31:16]=bf16(hi)
  uint32_t r; asm("v_cvt_pk_bf16_f32 %0, %1, %2" : "=v"(r) : "v"(lo), "v"(hi));
  return r;
}
// cross-half swap: a' = {a.lo, b.lo(partner)}, b' = {a.hi(partner), b.hi}
#if __has_builtin(__builtin_amdgcn_permlane32_swap)
DEVI void plswap(uint32_t& a, uint32_t& b) {
  u32x2 r = __builtin_amdgcn_permlane32_swap(a, b, false, false);
  a = r[0]; b = r[1];
}
#else
DEVI void plswap(uint32_t& a, uint32_t& b) {
  const int h = (threadIdx.x & 63) >> 5;
  const uint32_t pa = (uint32_t)__shfl_xor((int)a, 32);
  const uint32_t pb = (uint32_t)__shfl_xor((int)b, 32);
  const uint32_t na = h ? pb : a;
  const uint32_t nb = h ? b : pa;
  a = na; b = nb;
}
#endif
DEVI void gload16(const short* g, short* l) {
  __builtin_amdgcn_global_load_lds((const __attribute__((address_space(1))) uint32_t*)g,
                                   (__attribute__((address_space(3))) uint32_t*)l, 16, 0, 0);
}

// ---------------- fp32 -> bf16 conversion, up to 4 same-size tensors ----------
template <int LOG2G>
__global__ __launch_bounds__(256) void cvt3(const float* __restrict__ s0,
                                            const float* __restrict__ s1,
                                            const float* __restrict__ s2,
                                            const float* __restrict__ s3,
                                            short* __restrict__ d0,
                                            short* __restrict__ d1,
                                            short* __restrict__ d2,
                                            short* __restrict__ d3,
                                            int narr) {
  const int stride = gridDim.x * blockDim.x;
  const int total = narr << LOG2G;
  for (int g = blockIdx.x * blockDim.x + threadIdx.x; g < total; g += stride) {
    const int a = g >> LOG2G;
    const size_t off = (size_t)(g & ((1 << LOG2G) - 1)) * 8;
    const float* src = (a == 0) ? s0 : (a == 1) ? s1 : (a == 2) ? s2 : s3;
    short* dst = (a == 0) ? d0 : (a == 1) ? d1 : (a == 2) ? d2 : d3;
    const f32x4 x = *(const f32x4*)(src + off);
    const f32x4 y = *(const f32x4*)(src + off + 4);
    bf16x8 o;
#pragma unroll
    for (int e = 0; e < 4; ++e) { o[e] = f2bf(x[e]); o[e + 4] = f2bf(y[e]); }
    *(bf16x8*)(dst + off) = o;
  }
}

// ---------------- grouped QKV GEMM --------------------------------------------
// One launch, grid (M/128, D/128, 3): z=0 -> Q (scaleQ, row-major bf16),
// z=1 -> K (row-major bf16), z=2 -> V (transposed into Vt[(b*1024+n)][s]).
// 4 waves, 128x128 tile, BK=32, 16x16x32 MFMA, 2-phase dbuf + XOR swizzle
// (R6-proven body). 1536 blocks -> ~4 blocks/CU: occupancy unlocks the
// barrier-drain hiding the 512-block single GEMMs couldn't get.
__global__ __launch_bounds__(256) void gemm_qkv(const short* __restrict__ xq,
                                                const short* __restrict__ xk,
                                                const short* __restrict__ xv,
                                                const short* __restrict__ wq,
                                                const short* __restrict__ wk,
                                                const short* __restrict__ wv,
                                                const float* __restrict__ bq,
                                                const float* __restrict__ bk,
                                                const float* __restrict__ bv,
                                                short* __restrict__ Qf,
                                                short* __restrict__ Kf,
                                                short* __restrict__ Vt,
                                                float scaleQ) {
  __shared__ short sA[2][128 * 32];
  __shared__ short sB[2][128 * 32];
  const int z = blockIdx.z;
  const short* A  = (z == 0) ? xq : (z == 1) ? xk : xv;
  const short* Bw = (z == 0) ? wq : (z == 1) ? wk : wv;
  const float* bias = (z == 0) ? bq : (z == 1) ? bk : bv;

  const int tid = threadIdx.x;
  const int wid = tid >> 6, lane = tid & 63;
  const int m0 = blockIdx.x * 128, n0 = blockIdx.y * 128;
  const int wm = wid >> 1, wn = wid & 1;

  f32x4 acc[4][4];
#pragma unroll
  for (int i = 0; i < 4; ++i)
#pragma unroll
    for (int j = 0; j < 4; ++j) acc[i][j] = (f32x4){0.f, 0.f, 0.f, 0.f};

  const int srow = wid * 32 + (lane >> 2);
  const int swzs = (srow & 3) ^ ((srow >> 2) & 3);
  const int scol = ((lane & 3) ^ swzs) * 8;
  const short* gA = A + (size_t)(m0 + srow) * D_ + scol;
  const short* gB = Bw + (size_t)(n0 + srow) * D_ + scol;

  auto STAGE = [&](int bi, int kt) {
    short* la = &sA[bi][(wid * 32) * 32];
    short* lb = &sB[bi][(wid * 32) * 32];
    gload16(gA + kt, la);
    gload16(gA + (size_t)16 * D_ + kt, la + 16 * 32);
    gload16(gB + kt, lb);
    gload16(gB + (size_t)16 * D_ + kt, lb + 16 * 32);
  };

  STAGE(0, 0);
  __syncthreads();
  int cur = 0;

  const int swzf = (lane & 3) ^ ((lane >> 2) & 3);
  const int cofs = (((lane >> 4) ^ swzf) << 3);

  for (int kt = 0; kt < D_; kt += 32) {
    if (kt + 32 < D_) STAGE(cur ^ 1, kt + 32);
    bf16x8 af[4], bfr[4];
#pragma unroll
    for (int mf = 0; mf < 4; ++mf)
      af[mf] = *(const bf16x8*)&sA[cur][(wm * 64 + mf * 16 + (lane & 15)) * 32 + cofs];
#pragma unroll
    for (int nf = 0; nf < 4; ++nf)
      bfr[nf] = *(const bf16x8*)&sB[cur][(wn * 64 + nf * 16 + (lane & 15)) * 32 + cofs];
#pragma unroll
    for (int mf = 0; mf < 4; ++mf)
#pragma unroll
      for (int nf = 0; nf < 4; ++nf)
        acc[mf][nf] = __builtin_amdgcn_mfma_f32_16x16x32_bf16(af[mf], bfr[nf], acc[mf][nf], 0, 0, 0);
    __syncthreads();
    cur ^= 1;
  }

  const float scale = (z == 0) ? scaleQ : 1.0f;
  short* Cout = (z == 0) ? Qf : Kf;
#pragma unroll
  for (int mf = 0; mf < 4; ++mf) {
#pragma unroll
    for (int nf = 0; nf < 4; ++nf) {
      const int n = n0 + wn * 64 + nf * 16 + (lane & 15);
      const float bi = bias[n];
      if (z == 2) {
        const int m_base = m0 + wm * 64 + mf * 16 + ((lane >> 4) * 4);
        const int b = m_base >> 11, s0 = m_base & 2047;
        s16x4 pk;
#pragma unroll
        for (int r = 0; r < 4; ++r) pk[r] = f2bf(acc[mf][nf][r] + bi);
        *(s16x4*)(Vt + ((size_t)(b * 1024 + n)) * 2048 + s0) = pk;
      } else {
#pragma unroll
        for (int r = 0; r < 4; ++r) {
          const int m = m0 + wm * 64 + mf * 16 + ((lane >> 4) * 4) + r;
          Cout[(size_t)m * D_ + n] = f2bf((acc[mf][nf][r] + bi) * scale);
        }
      }
    }
  }
}

// ---------------- bf16 GEMM (O-projection): 8 waves, f32 out -------------------
template <int MODE>
__global__ __launch_bounds__(512, 4) void gemm_bt(const short* __restrict__ A,
                                                  const short* __restrict__ Bw,
                                                  const float* __restrict__ bias,
                                                  void* __restrict__ Cout,
                                                  int Kdim, int Ndim, float scale) {
  __shared__ short sA[2][128 * 32];
  __shared__ short sB[2][128 * 32];
  const int tid = threadIdx.x;
  const int wid = tid >> 6, lane = tid & 63;
  const int m0 = blockIdx.x * 128, n0 = blockIdx.y * 128;
  const int wm = wid >> 1, wn = wid & 1;  // 4 x 2 wave grid, 32x64 per wave

  f32x4 acc[2][4];
#pragma unroll
  for (int i = 0; i < 2; ++i)
#pragma unroll
    for (int j = 0; j < 4; ++j) acc[i][j] = (f32x4){0.f, 0.f, 0.f, 0.f};

  const int srow = wid * 16 + (lane >> 2);
  const int swzs = (srow & 3) ^ ((srow >> 2) & 3);
  const int scol = ((lane & 3) ^ swzs) * 8;
  const short* gA = A + (size_t)(m0 + srow) * Kdim + scol;
  const short* gB = Bw + (size_t)(n0 + srow) * Kdim + scol;

  auto STAGE = [&](int bi, int kt) {
    gload16(gA + kt, &sA[bi][(wid * 16) * 32]);
    gload16(gB + kt, &sB[bi][(wid * 16) * 32]);
  };

  STAGE(0, 0);
  __syncthreads();
  int cur = 0;

  const int swzf = (lane & 3) ^ ((lane >> 2) & 3);
  const int cofs = (((lane >> 4) ^ swzf) << 3);

  for (int kt = 0; kt < Kdim; kt += 32) {
    if (kt + 32 < Kdim) STAGE(cur ^ 1, kt + 32);
    bf16x8 af[2], bfr[4];
#pragma unroll
    for (int mf = 0; mf < 2; ++mf)
      af[mf] = *(const bf16x8*)&sA[cur][(wm * 32 + mf * 16 + (lane & 15)) * 32 + cofs];
#pragma unroll
    for (int nf = 0; nf < 4; ++nf)
      bfr[nf] = *(const bf16x8*)&sB[cur][(wn * 64 + nf * 16 + (lane & 15)) * 32 + cofs];
#pragma unroll
    for (int mf = 0; mf < 2; ++mf)
#pragma unroll
      for (int nf = 0; nf < 4; ++nf)
        acc[mf][nf] = __builtin_amdgcn_mfma_f32_16x16x32_bf16(af[mf], bfr[nf], acc[mf][nf], 0, 0, 0);
    __syncthreads();
    cur ^= 1;
  }

#pragma unroll
  for (int mf = 0; mf < 2; ++mf) {
#pragma unroll
    for (int nf = 0; nf < 4; ++nf) {
      const int n = n0 + wn * 64 + nf * 16 + (lane & 15);
      const float bi = bias[n];
#pragma unroll
      for (int r = 0; r < 4; ++r) {
        const int m = m0 + wm * 32 + mf * 16 + ((lane >> 4) * 4) + r;
        const float vv = (acc[mf][nf][r] + bi) * scale;
        if (MODE == 0)
          ((short*)Cout)[(size_t)m * Ndim + n] = f2bf(vv);
        else
          ((float*)Cout)[(size_t)m * Ndim + n] = vv;
      }
    }
  }
}

// ---------------- causal flash attention (R8 proven) ---------------------------
__global__ __launch_bounds__(512, 4) void attn_fwd(const short* __restrict__ Qf,
                                                   const short* __restrict__ Kf,
                                                   const short* __restrict__ Vt,
                                                   short* __restrict__ AO) {
  __shared__ short sK[2][64 * 64];   // [key][d], swizzled chunks
  __shared__ short sV[2][64 * 64];   // [d][key], swizzled chunks

  const int tid = threadIdx.x, wid = tid >> 6, lane = tid & 63;
  const int h = lane >> 5, ql = lane & 31;
  const int cpx = gridDim.x >> 3;
  const int wg = ((int)blockIdx.x & 7) * cpx + ((int)blockIdx.x >> 3);
  const int bh = wg >> 3;
  const int pi = wg & 7;
  const int b = bh >> 4, hd = bh & 15;
  const int panel = (wid < 4) ? (15 - pi) : pi;
  const int qw = panel * 128 + (wid & 3) * 32;
  const int qg = qw + ql;
  const size_t rowbase = (size_t)b * S_ * D_ + (size_t)hd * DK_;
  const size_t vbase = (size_t)bh * 64 * S_;

  bf16x8 aQ[4];
  {
    const short* qp = Qf + rowbase + (size_t)qg * D_ + h * 8;
#pragma unroll
    for (int d = 0; d < 4; ++d) aQ[d] = *(const bf16x8*)(qp + d * 16);
  }

  f32x16 o0, o1;
#pragma unroll
  for (int i = 0; i < 16; ++i) { o0[i] = 0.f; o1[i] = 0.f; }
  float m_run = -1e30f, lsum = 0.f;

  const int srow8 = lane >> 3;
  const int schunk = ((lane & 7) ^ srow8) * 8;
  const short* gK = Kf + rowbase + (size_t)(wid * 8 + srow8) * D_ + schunk;
  const short* gV = Vt + vbase + (size_t)(wid * 8 + srow8) * S_ + schunk;

  auto STAGE = [&](int bufi, int kt) {
    gload16(gK + (size_t)kt * D_, &sK[bufi][(wid * 8) * 64]);
    gload16(gV + kt, &sV[bufi][(wid * 8) * 64]);
  };

  const int nt = 32 - 2 * pi;
  STAGE(0, 0);
  __syncthreads();
  int cur = 0;

  const int swz = ((ql & 7) << 3);  // row swizzle (same for ql and 32+ql)

  for (int t = 0; t < nt; ++t) {
    const int kt = t * 64;
    if (t + 1 < nt) STAGE(cur ^ 1, kt + 64);
    if (kt <= qw + 31) {
      const short* bK = &sK[cur][0];
      const short* bV = &sV[cur][0];
      // ---- QK^T swapped: p = P[key][q=qg], in-loop frag loads ----
      f32x16 p0, p1;
#pragma unroll
      for (int i = 0; i < 16; ++i) { p0[i] = 0.f; p1[i] = 0.f; }
      __builtin_amdgcn_s_setprio(1);
#pragma unroll
      for (int d = 0; d < 4; ++d) {
        const int co = ((d * 2 + h) << 3) ^ swz;
        bf16x8 k0 = *(const bf16x8*)&bK[ql * 64 + co];
        bf16x8 k1 = *(const bf16x8*)&bK[(32 + ql) * 64 + co];
        p0 = __builtin_amdgcn_mfma_f32_32x32x16_bf16(k0, aQ[d], p0, 0, 0, 0);
        p1 = __builtin_amdgcn_mfma_f32_32x32x16_bf16(k1, aQ[d], p1, 0, 0, 0);
      }
      __builtin_amdgcn_s_setprio(0);
      // ---- causal mask (diagonal tiles only) ----
      if (kt + 63 > qw) {
        const int qk = qg - kt;
#pragma unroll
        for (int i = 0; i < 16; ++i) {
          const int k0i = 8 * (i >> 2) + 4 * h + (i & 3);
          if (k0i > qk) p0[i] = -1e30f;
          if (k0i + 32 > qk) p1[i] = -1e30f;
        }
      }
      // ---- row max: register tree (depth 5) + cross-half shfl ----
      float tr[8];
#pragma unroll
      for (int i = 0; i < 8; ++i)
        tr[i] = fmaxf(fmaxf(p0[i], p0[i + 8]), fmaxf(p1[i], p1[i + 8]));
#pragma unroll
      for (int s = 4; s > 0; s >>= 1)
#pragma unroll
        for (int i = 0; i < s; ++i) tr[i] = fmaxf(tr[i], tr[i + s]);
      float mx = fmaxf(tr[0], __shfl_xor(tr[0], 32));
      // ---- defer-max rescale ----
      if (mx > m_run + 8.f) {
        const float corr = exp2_hw(m_run - mx);
        m_run = mx;
        lsum *= corr;
#pragma unroll
        for (int i = 0; i < 16; ++i) { o0[i] *= corr; o1[i] *= corr; }
      }
      // ---- exp + sum tree ----
#pragma unroll
      for (int i = 0; i < 16; ++i) {
        p0[i] = exp2_hw(p0[i] - m_run);
        p1[i] = exp2_hw(p1[i] - m_run);
      }
      float sr[8];
#pragma unroll
      for (int i = 0; i < 8; ++i) sr[i] = (p0[i] + p0[i + 8]) + (p1[i] + p1[i + 8]);
#pragma unroll
      for (int s = 4; s > 0; s >>= 1)
#pragma unroll
        for (int i = 0; i < s; ++i) sr[i] += sr[i + s];
      lsum += sr[0] + __shfl_xor(sr[0], 32);
      // ---- pack P to bf16 pairs ----
      uint32_t cj[8], dj[8];
#pragma unroll
      for (int j = 0; j < 4; ++j) {
        cj[j]     = cvtpk(p0[4 * j], p0[4 * j + 1]);
        dj[j]     = cvtpk(p0[4 * j + 2], p0[4 * j + 3]);
        cj[4 + j] = cvtpk(p1[4 * j], p1[4 * j + 1]);
        dj[4 + j] = cvtpk(p1[4 * j + 2], p1[4 * j + 3]);
      }
      // ---- PV swapped: cross-half exchange via permlane32_swap, in-loop V ----
      __builtin_amdgcn_s_setprio(1);
#pragma unroll
      for (int m = 0; m < 4; ++m) {
        uint32_t w0 = cj[2 * m], w2 = cj[2 * m + 1];
        plswap(w0, w2);
        uint32_t w1 = dj[2 * m], w3 = dj[2 * m + 1];
        plswap(w1, w3);
        union { uint32_t w[4]; bf16x8 v; } u;
        u.w[0] = w0; u.w[1] = w1; u.w[2] = w2; u.w[3] = w3;
        const int co = ((m * 2 + h) << 3) ^ swz;
        bf16x8 v0 = *(const bf16x8*)&bV[ql * 64 + co];
        bf16x8 v1 = *(const bf16x8*)&bV[(32 + ql) * 64 + co];
        o0 = __builtin_amdgcn_mfma_f32_32x32x16_bf16(v0, u.v, o0, 0, 0, 0);
        o1 = __builtin_amdgcn_mfma_f32_32x32x16_bf16(v1, u.v, o1, 0, 0, 0);
      }
      __builtin_amdgcn_s_setprio(0);
    }
    __syncthreads();  // drains vmcnt(0): tile t+1 landed; all done reading cur
    cur ^= 1;
  }

  // ---- epilogue ----
  const float invl = 1.f / lsum;
  short* op = AO + rowbase + (size_t)qg * D_;
#pragma unroll
  for (int j = 0; j < 4; ++j) {
    s16x4 w0, w1;
#pragma unroll
    for (int r = 0; r < 4; ++r) {
      w0[r] = f2bf(o0[4 * j + r] * invl);
      w1[r] = f2bf(o1[4 * j + r] * invl);
    }
    *(s16x4*)(op + 8 * j + 4 * h) = w0;
    *(s16x4*)(op + 32 + 8 * j + 4 * h) = w1;
  }
}

// ---------------- launch -------------------------------------------------------
extern "C" void kernel_launch(void* const* d_in, const int* in_sizes, int n_in,
                              void* d_out, int out_size, void* d_ws, size_t ws_size,
                              hipStream_t stream) {
  (void)in_sizes; (void)n_in; (void)out_size; (void)ws_size;
  const float* q  = (const float*)d_in[0];
  const float* k  = (const float*)d_in[1];
  const float* v  = (const float*)d_in[2];
  const float* Wq = (const float*)d_in[4];
  const float* bq = (const float*)d_in[5];
  const float* Wk = (const float*)d_in[6];
  const float* bk = (const float*)d_in[7];
  const float* Wv = (const float*)d_in[8];
  const float* bv = (const float*)d_in[9];
  const float* Wo = (const float*)d_in[10];
  const float* bo = (const float*)d_in[11];

  char* ws = (char*)d_ws;
  const size_t MB = 1ull << 20;
  short* wqb = (short*)(ws + 0 * MB);
  short* wkb = (short*)(ws + 2 * MB);
  short* wvb = (short*)(ws + 4 * MB);
  short* wob = (short*)(ws + 6 * MB);
  short* Qf  = (short*)(ws + 8 * MB);
  short* Kf  = (short*)(ws + 24 * MB);
  short* Vtb = (short*)(ws + 40 * MB);  // transposed V: [(b*1024+n)][s]
  short* xq  = (short*)(ws + 56 * MB);
  short* xk  = (short*)(ws + 72 * MB);
  short* xv  = (short*)(ws + 88 * MB);
  short* AO  = xq;

  // fused conversions: {q,k,v} (BSD/8 = 2^20 groups each), 4 weights (2^17 each)
  cvt3<20><<<2048, 256, 0, stream>>>(q, k, v, v, xq, xk, xv, xv, 3);
  cvt3<17><<<1024, 256, 0, stream>>>(Wq, Wk, Wv, Wo, wqb, wkb, wvb, wob, 4);

  // grouped QKV projections: one launch, 1536 blocks (~4 blocks/CU).
  // Q folds 1/sqrt(DK) * log2(e) so softmax runs in base-2.
  gemm_qkv<<<dim3(M_ / 128, D_ / 128, 3), 256, 0, stream>>>(
      xq, xk, xv, wqb, wkb, wvb, bq, bk, bv, Qf, Kf, Vtb,
      0.125f * 1.4426950408889634f);

  attn_fwd<<<dim3(512), 512, 0, stream>>>(Qf, Kf, Vtb, AO);

  gemm_bt<1><<<dim3(M_ / 128, D_ / 128), 512, 0, stream>>>(AO, wob, bo, d_out, D_, D_, 1.0f);
}

// Round 10
// 183.619 us; speedup vs baseline: 1.2381x; 1.0294x over previous
//
#include <hip/hip_runtime.h>
#include <stdint.h>

typedef __attribute__((ext_vector_type(8))) short bf16x8;
typedef __attribute__((ext_vector_type(4))) short s16x4;
typedef __attribute__((ext_vector_type(4))) float f32x4;
typedef __attribute__((ext_vector_type(16))) float f32x16;
typedef __attribute__((ext_vector_type(2))) unsigned u32x2;

#define DEVI __device__ __forceinline__

constexpr int B_ = 4, S_ = 2048, D_ = 1024, H_ = 16, DK_ = 64;
constexpr int M_ = B_ * S_;  // 8192 rows total

DEVI short f2bf(float f) {
  union { float f; uint32_t u; } x; x.f = f;
  uint32_t r = x.u + 0x7fffu + ((x.u >> 16) & 1u);  // RNE
  return (short)(uint16_t)(r >> 16);
}
DEVI float exp2_hw(float x) {  // v_exp_f32 is 2^x
  float r; asm("v_exp_f32 %0, %1" : "=v"(r) : "v"(x)); return r;
}
DEVI uint32_t cvtpk(float lo, float hi) {  // [15:0]=bf16(lo), [31:16]=bf16(hi)
  uint32_t r; asm("v_cvt_pk_bf16_f32 %0, %1, %2" : "=v"(r) : "v"(lo), "v"(hi));
  return r;
}
// cross-half swap: a' = {a.lo, b.lo(partner)}, b' = {a.hi(partner), b.hi}
#if __has_builtin(__builtin_amdgcn_permlane32_swap)
DEVI void plswap(uint32_t& a, uint32_t& b) {
  u32x2 r = __builtin_amdgcn_permlane32_swap(a, b, false, false);
  a = r[0]; b = r[1];
}
#else
DEVI void plswap(uint32_t& a, uint32_t& b) {
  const int h = (threadIdx.x & 63) >> 5;
  const uint32_t pa = (uint32_t)__shfl_xor((int)a, 32);
  const uint32_t pb = (uint32_t)__shfl_xor((int)b, 32);
  const uint32_t na = h ? pb : a;
  const uint32_t nb = h ? b : pa;
  a = na; b = nb;
}
#endif
DEVI void gload16(const short* g, short* l) {
  __builtin_amdgcn_global_load_lds((const __attribute__((address_space(1))) uint32_t*)g,
                                   (__attribute__((address_space(3))) uint32_t*)l, 16, 0, 0);
}

// ---------------- fp32 -> bf16 conversion, up to 4 same-size tensors ----------
template <int LOG2G>
__global__ __launch_bounds__(256) void cvt3(const float* __restrict__ s0,
                                            const float* __restrict__ s1,
                                            const float* __restrict__ s2,
                                            const float* __restrict__ s3,
                                            short* __restrict__ d0,
                                            short* __restrict__ d1,
                                            short* __restrict__ d2,
                                            short* __restrict__ d3,
                                            int narr) {
  const int stride = gridDim.x * blockDim.x;
  const int total = narr << LOG2G;
  for (int g = blockIdx.x * blockDim.x + threadIdx.x; g < total; g += stride) {
    const int a = g >> LOG2G;
    const size_t off = (size_t)(g & ((1 << LOG2G) - 1)) * 8;
    const float* src = (a == 0) ? s0 : (a == 1) ? s1 : (a == 2) ? s2 : s3;
    short* dst = (a == 0) ? d0 : (a == 1) ? d1 : (a == 2) ? d2 : d3;
    const f32x4 x = *(const f32x4*)(src + off);
    const f32x4 y = *(const f32x4*)(src + off + 4);
    bf16x8 o;
#pragma unroll
    for (int e = 0; e < 4; ++e) { o[e] = f2bf(x[e]); o[e + 4] = f2bf(y[e]); }
    *(bf16x8*)(dst + off) = o;
  }
}

// ---------------- grouped QKV GEMM --------------------------------------------
// Grid (M/128, D/128, 3): z=0 -> Q (scaleQ), z=1 -> K, z=2 -> V (transposed).
// 4 waves, 128x128 tile, BK=32, 16x16x32 MFMA. TRIPLE-buffered LDS pipeline:
// STAGE(t+2) issued before compute(t); counted vmcnt(4) (never 0 mid-loop) +
// raw s_barrier -> prefetch loads stay in flight ACROSS the barrier (T3/T4).
__global__ __launch_bounds__(256, 3) void gemm_qkv(const short* __restrict__ xq,
                                                   const short* __restrict__ xk,
                                                   const short* __restrict__ xv,
                                                   const short* __restrict__ wq,
                                                   const short* __restrict__ wk,
                                                   const short* __restrict__ wv,
                                                   const float* __restrict__ bq,
                                                   const float* __restrict__ bk,
                                                   const float* __restrict__ bv,
                                                   short* __restrict__ Qf,
                                                   short* __restrict__ Kf,
                                                   short* __restrict__ Vt,
                                                   float scaleQ) {
  __shared__ short sA[3][128 * 32];
  __shared__ short sB[3][128 * 32];
  const int z = blockIdx.z;
  const short* A  = (z == 0) ? xq : (z == 1) ? xk : xv;
  const short* Bw = (z == 0) ? wq : (z == 1) ? wk : wv;
  const float* bias = (z == 0) ? bq : (z == 1) ? bk : bv;

  const int tid = threadIdx.x;
  const int wid = tid >> 6, lane = tid & 63;
  const int m0 = blockIdx.x * 128, n0 = blockIdx.y * 128;
  const int wm = wid >> 1, wn = wid & 1;

  f32x4 acc[4][4];
#pragma unroll
  for (int i = 0; i < 4; ++i)
#pragma unroll
    for (int j = 0; j < 4; ++j) acc[i][j] = (f32x4){0.f, 0.f, 0.f, 0.f};

  const int srow = wid * 32 + (lane >> 2);
  const int swzs = (srow & 3) ^ ((srow >> 2) & 3);
  const int scol = ((lane & 3) ^ swzs) * 8;
  const short* gA = A + (size_t)(m0 + srow) * D_ + scol;
  const short* gB = Bw + (size_t)(n0 + srow) * D_ + scol;

  auto STAGE = [&](int bi, int kt) {  // 4 loads/wave
    short* la = &sA[bi][(wid * 32) * 32];
    short* lb = &sB[bi][(wid * 32) * 32];
    gload16(gA + kt, la);
    gload16(gA + (size_t)16 * D_ + kt, la + 16 * 32);
    gload16(gB + kt, lb);
    gload16(gB + (size_t)16 * D_ + kt, lb + 16 * 32);
  };

  STAGE(0, 0);
  STAGE(1, 32);
  asm volatile("s_waitcnt vmcnt(4)" ::: "memory");  // buf0 landed; buf1 in flight
  __builtin_amdgcn_s_barrier();

  const int swzf = (lane & 3) ^ ((lane >> 2) & 3);
  const int cofs = (((lane >> 4) ^ swzf) << 3);

  int cur = 0, nxt = 1, stg = 2;
  for (int t = 0; t < 32; ++t) {
    if (t + 2 < 32) STAGE(stg, (t + 2) * 32);  // overwrites buffer read at t-1 (safe post-barrier)
    bf16x8 af[4], bfr[4];
#pragma unroll
    for (int mf = 0; mf < 4; ++mf)
      af[mf] = *(const bf16x8*)&sA[cur][(wm * 64 + mf * 16 + (lane & 15)) * 32 + cofs];
#pragma unroll
    for (int nf = 0; nf < 4; ++nf)
      bfr[nf] = *(const bf16x8*)&sB[cur][(wn * 64 + nf * 16 + (lane & 15)) * 32 + cofs];
#pragma unroll
    for (int mf = 0; mf < 4; ++mf)
#pragma unroll
      for (int nf = 0; nf < 4; ++nf)
        acc[mf][nf] = __builtin_amdgcn_mfma_f32_16x16x32_bf16(af[mf], bfr[nf], acc[mf][nf], 0, 0, 0);
    if (t + 2 < 32) {
      // outstanding <= 8 (t+1's 4 + t+2's 4): vmcnt(4) => t+1 landed, t+2 in flight
      asm volatile("s_waitcnt vmcnt(4)" ::: "memory");
      __builtin_amdgcn_s_barrier();
    } else if (t + 1 < 32) {
      asm volatile("s_waitcnt vmcnt(0)" ::: "memory");  // tail: no new issue
      __builtin_amdgcn_s_barrier();
    }
    const int tmp = cur; cur = nxt; nxt = stg; stg = tmp;
  }

  const float scale = (z == 0) ? scaleQ : 1.0f;
  short* Cout = (z == 0) ? Qf : Kf;
#pragma unroll
  for (int mf = 0; mf < 4; ++mf) {
#pragma unroll
    for (int nf = 0; nf < 4; ++nf) {
      const int n = n0 + wn * 64 + nf * 16 + (lane & 15);
      const float bi = bias[n];
      if (z == 2) {
        const int m_base = m0 + wm * 64 + mf * 16 + ((lane >> 4) * 4);
        const int b = m_base >> 11, s0 = m_base & 2047;
        s16x4 pk;
#pragma unroll
        for (int r = 0; r < 4; ++r) pk[r] = f2bf(acc[mf][nf][r] + bi);
        *(s16x4*)(Vt + ((size_t)(b * 1024 + n)) * 2048 + s0) = pk;
      } else {
#pragma unroll
        for (int r = 0; r < 4; ++r) {
          const int m = m0 + wm * 64 + mf * 16 + ((lane >> 4) * 4) + r;
          Cout[(size_t)m * D_ + n] = f2bf((acc[mf][nf][r] + bi) * scale);
        }
      }
    }
  }
}

// ---------------- O-projection GEMM: 8 waves, f32 out, same T3/T4 pipeline ----
__global__ __launch_bounds__(512, 4) void gemm_o(const short* __restrict__ A,
                                                 const short* __restrict__ Bw,
                                                 const float* __restrict__ bias,
                                                 float* __restrict__ Cout) {
  __shared__ short sA[3][128 * 32];
  __shared__ short sB[3][128 * 32];
  const int tid = threadIdx.x;
  const int wid = tid >> 6, lane = tid & 63;
  const int m0 = blockIdx.x * 128, n0 = blockIdx.y * 128;
  const int wm = wid >> 1, wn = wid & 1;  // 4 x 2 wave grid, 32x64 per wave

  f32x4 acc[2][4];
#pragma unroll
  for (int i = 0; i < 2; ++i)
#pragma unroll
    for (int j = 0; j < 4; ++j) acc[i][j] = (f32x4){0.f, 0.f, 0.f, 0.f};

  const int srow = wid * 16 + (lane >> 2);
  const int swzs = (srow & 3) ^ ((srow >> 2) & 3);
  const int scol = ((lane & 3) ^ swzs) * 8;
  const short* gA = A + (size_t)(m0 + srow) * D_ + scol;
  const short* gB = Bw + (size_t)(n0 + srow) * D_ + scol;

  auto STAGE = [&](int bi, int kt) {  // 2 loads/wave
    gload16(gA + kt, &sA[bi][(wid * 16) * 32]);
    gload16(gB + kt, &sB[bi][(wid * 16) * 32]);
  };

  STAGE(0, 0);
  STAGE(1, 32);
  asm volatile("s_waitcnt vmcnt(2)" ::: "memory");
  __builtin_amdgcn_s_barrier();

  const int swzf = (lane & 3) ^ ((lane >> 2) & 3);
  const int cofs = (((lane >> 4) ^ swzf) << 3);

  int cur = 0, nxt = 1, stg = 2;
  for (int t = 0; t < 32; ++t) {
    if (t + 2 < 32) STAGE(stg, (t + 2) * 32);
    bf16x8 af[2], bfr[4];
#pragma unroll
    for (int mf = 0; mf < 2; ++mf)
      af[mf] = *(const bf16x8*)&sA[cur][(wm * 32 + mf * 16 + (lane & 15)) * 32 + cofs];
#pragma unroll
    for (int nf = 0; nf < 4; ++nf)
      bfr[nf] = *(const bf16x8*)&sB[cur][(wn * 64 + nf * 16 + (lane & 15)) * 32 + cofs];
#pragma unroll
    for (int mf = 0; mf < 2; ++mf)
#pragma unroll
      for (int nf = 0; nf < 4; ++nf)
        acc[mf][nf] = __builtin_amdgcn_mfma_f32_16x16x32_bf16(af[mf], bfr[nf], acc[mf][nf], 0, 0, 0);
    if (t + 2 < 32) {
      asm volatile("s_waitcnt vmcnt(2)" ::: "memory");
      __builtin_amdgcn_s_barrier();
    } else if (t + 1 < 32) {
      asm volatile("s_waitcnt vmcnt(0)" ::: "memory");
      __builtin_amdgcn_s_barrier();
    }
    const int tmp = cur; cur = nxt; nxt = stg; stg = tmp;
  }

#pragma unroll
  for (int mf = 0; mf < 2; ++mf) {
#pragma unroll
    for (int nf = 0; nf < 4; ++nf) {
      const int n = n0 + wn * 64 + nf * 16 + (lane & 15);
      const float bi = bias[n];
#pragma unroll
      for (int r = 0; r < 4; ++r) {
        const int m = m0 + wm * 32 + mf * 16 + ((lane >> 4) * 4) + r;
        Cout[(size_t)m * D_ + n] = acc[mf][nf][r] + bi;
      }
    }
  }
}

// ---------------- causal flash attention (R8/R9 proven, unchanged) -------------
__global__ __launch_bounds__(512, 4) void attn_fwd(const short* __restrict__ Qf,
                                                   const short* __restrict__ Kf,
                                                   const short* __restrict__ Vt,
                                                   short* __restrict__ AO) {
  __shared__ short sK[2][64 * 64];   // [key][d], swizzled chunks
  __shared__ short sV[2][64 * 64];   // [d][key], swizzled chunks

  const int tid = threadIdx.x, wid = tid >> 6, lane = tid & 63;
  const int h = lane >> 5, ql = lane & 31;
  const int cpx = gridDim.x >> 3;
  const int wg = ((int)blockIdx.x & 7) * cpx + ((int)blockIdx.x >> 3);
  const int bh = wg >> 3;
  const int pi = wg & 7;
  const int b = bh >> 4, hd = bh & 15;
  const int panel = (wid < 4) ? (15 - pi) : pi;
  const int qw = panel * 128 + (wid & 3) * 32;
  const int qg = qw + ql;
  const size_t rowbase = (size_t)b * S_ * D_ + (size_t)hd * DK_;
  const size_t vbase = (size_t)bh * 64 * S_;

  bf16x8 aQ[4];
  {
    const short* qp = Qf + rowbase + (size_t)qg * D_ + h * 8;
#pragma unroll
    for (int d = 0; d < 4; ++d) aQ[d] = *(const bf16x8*)(qp + d * 16);
  }

  f32x16 o0, o1;
#pragma unroll
  for (int i = 0; i < 16; ++i) { o0[i] = 0.f; o1[i] = 0.f; }
  float m_run = -1e30f, lsum = 0.f;

  const int srow8 = lane >> 3;
  const int schunk = ((lane & 7) ^ srow8) * 8;
  const short* gK = Kf + rowbase + (size_t)(wid * 8 + srow8) * D_ + schunk;
  const short* gV = Vt + vbase + (size_t)(wid * 8 + srow8) * S_ + schunk;

  auto STAGE = [&](int bufi, int kt) {
    gload16(gK + (size_t)kt * D_, &sK[bufi][(wid * 8) * 64]);
    gload16(gV + kt, &sV[bufi][(wid * 8) * 64]);
  };

  const int nt = 32 - 2 * pi;
  STAGE(0, 0);
  __syncthreads();
  int cur = 0;

  const int swz = ((ql & 7) << 3);  // row swizzle (same for ql and 32+ql)

  for (int t = 0; t < nt; ++t) {
    const int kt = t * 64;
    if (t + 1 < nt) STAGE(cur ^ 1, kt + 64);
    if (kt <= qw + 31) {
      const short* bK = &sK[cur][0];
      const short* bV = &sV[cur][0];
      // ---- QK^T swapped: p = P[key][q=qg], in-loop frag loads ----
      f32x16 p0, p1;
#pragma unroll
      for (int i = 0; i < 16; ++i) { p0[i] = 0.f; p1[i] = 0.f; }
      __builtin_amdgcn_s_setprio(1);
#pragma unroll
      for (int d = 0; d < 4; ++d) {
        const int co = ((d * 2 + h) << 3) ^ swz;
        bf16x8 k0 = *(const bf16x8*)&bK[ql * 64 + co];
        bf16x8 k1 = *(const bf16x8*)&bK[(32 + ql) * 64 + co];
        p0 = __builtin_amdgcn_mfma_f32_32x32x16_bf16(k0, aQ[d], p0, 0, 0, 0);
        p1 = __builtin_amdgcn_mfma_f32_32x32x16_bf16(k1, aQ[d], p1, 0, 0, 0);
      }
      __builtin_amdgcn_s_setprio(0);
      // ---- causal mask (diagonal tiles only) ----
      if (kt + 63 > qw) {
        const int qk = qg - kt;
#pragma unroll
        for (int i = 0; i < 16; ++i) {
          const int k0i = 8 * (i >> 2) + 4 * h + (i & 3);
          if (k0i > qk) p0[i] = -1e30f;
          if (k0i + 32 > qk) p1[i] = -1e30f;
        }
      }
      // ---- row max: register tree (depth 5) + cross-half shfl ----
      float tr[8];
#pragma unroll
      for (int i = 0; i < 8; ++i)
        tr[i] = fmaxf(fmaxf(p0[i], p0[i + 8]), fmaxf(p1[i], p1[i + 8]));
#pragma unroll
      for (int s = 4; s > 0; s >>= 1)
#pragma unroll
        for (int i = 0; i < s; ++i) tr[i] = fmaxf(tr[i], tr[i + s]);
      float mx = fmaxf(tr[0], __shfl_xor(tr[0], 32));
      // ---- defer-max rescale ----
      if (mx > m_run + 8.f) {
        const float corr = exp2_hw(m_run - mx);
        m_run = mx;
        lsum *= corr;
#pragma unroll
        for (int i = 0; i < 16; ++i) { o0[i] *= corr; o1[i] *= corr; }
      }
      // ---- exp + sum tree ----
#pragma unroll
      for (int i = 0; i < 16; ++i) {
        p0[i] = exp2_hw(p0[i] - m_run);
        p1[i] = exp2_hw(p1[i] - m_run);
      }
      float sr[8];
#pragma unroll
      for (int i = 0; i < 8; ++i) sr[i] = (p0[i] + p0[i + 8]) + (p1[i] + p1[i + 8]);
#pragma unroll
      for (int s = 4; s > 0; s >>= 1)
#pragma unroll
        for (int i = 0; i < s; ++i) sr[i] += sr[i + s];
      lsum += sr[0] + __shfl_xor(sr[0], 32);
      // ---- pack P to bf16 pairs ----
      uint32_t cj[8], dj[8];
#pragma unroll
      for (int j = 0; j < 4; ++j) {
        cj[j]     = cvtpk(p0[4 * j], p0[4 * j + 1]);
        dj[j]     = cvtpk(p0[4 * j + 2], p0[4 * j + 3]);
        cj[4 + j] = cvtpk(p1[4 * j], p1[4 * j + 1]);
        dj[4 + j] = cvtpk(p1[4 * j + 2], p1[4 * j + 3]);
      }
      // ---- PV swapped: cross-half exchange via permlane32_swap, in-loop V ----
      __builtin_amdgcn_s_setprio(1);
#pragma unroll
      for (int m = 0; m < 4; ++m) {
        uint32_t w0 = cj[2 * m], w2 = cj[2 * m + 1];
        plswap(w0, w2);
        uint32_t w1 = dj[2 * m], w3 = dj[2 * m + 1];
        plswap(w1, w3);
        union { uint32_t w[4]; bf16x8 v; } u;
        u.w[0] = w0; u.w[1] = w1; u.w[2] = w2; u.w[3] = w3;
        const int co = ((m * 2 + h) << 3) ^ swz;
        bf16x8 v0 = *(const bf16x8*)&bV[ql * 64 + co];
        bf16x8 v1 = *(const bf16x8*)&bV[(32 + ql) * 64 + co];
        o0 = __builtin_amdgcn_mfma_f32_32x32x16_bf16(v0, u.v, o0, 0, 0, 0);
        o1 = __builtin_amdgcn_mfma_f32_32x32x16_bf16(v1, u.v, o1, 0, 0, 0);
      }
      __builtin_amdgcn_s_setprio(0);
    }
    __syncthreads();  // drains vmcnt(0): tile t+1 landed; all done reading cur
    cur ^= 1;
  }

  // ---- epilogue ----
  const float invl = 1.f / lsum;
  short* op = AO + rowbase + (size_t)qg * D_;
#pragma unroll
  for (int j = 0; j < 4; ++j) {
    s16x4 w0, w1;
#pragma unroll
    for (int r = 0; r < 4; ++r) {
      w0[r] = f2bf(o0[4 * j + r] * invl);
      w1[r] = f2bf(o1[4 * j + r] * invl);
    }
    *(s16x4*)(op + 8 * j + 4 * h) = w0;
    *(s16x4*)(op + 32 + 8 * j + 4 * h) = w1;
  }
}

// ---------------- launch -------------------------------------------------------
extern "C" void kernel_launch(void* const* d_in, const int* in_sizes, int n_in,
                              void* d_out, int out_size, void* d_ws, size_t ws_size,
                              hipStream_t stream) {
  (void)in_sizes; (void)n_in; (void)out_size; (void)ws_size;
  const float* q  = (const float*)d_in[0];
  const float* k  = (const float*)d_in[1];
  const float* v  = (const float*)d_in[2];
  const float* Wq = (const float*)d_in[4];
  const float* bq = (const float*)d_in[5];
  const float* Wk = (const float*)d_in[6];
  const float* bk = (const float*)d_in[7];
  const float* Wv = (const float*)d_in[8];
  const float* bv = (const float*)d_in[9];
  const float* Wo = (const float*)d_in[10];
  const float* bo = (const float*)d_in[11];

  char* ws = (char*)d_ws;
  const size_t MB = 1ull << 20;
  short* wqb = (short*)(ws + 0 * MB);
  short* wkb = (short*)(ws + 2 * MB);
  short* wvb = (short*)(ws + 4 * MB);
  short* wob = (short*)(ws + 6 * MB);
  short* Qf  = (short*)(ws + 8 * MB);
  short* Kf  = (short*)(ws + 24 * MB);
  short* Vtb = (short*)(ws + 40 * MB);  // transposed V: [(b*1024+n)][s]
  short* xq  = (short*)(ws + 56 * MB);
  short* xk  = (short*)(ws + 72 * MB);
  short* xv  = (short*)(ws + 88 * MB);
  short* AO  = xq;

  // fused conversions: {q,k,v} (BSD/8 = 2^20 groups each), 4 weights (2^17 each)
  cvt3<20><<<2048, 256, 0, stream>>>(q, k, v, v, xq, xk, xv, xv, 3);
  cvt3<17><<<1024, 256, 0, stream>>>(Wq, Wk, Wv, Wo, wqb, wkb, wvb, wob, 4);

  // grouped QKV projections: one launch, 1536 blocks, T3/T4 counted-vmcnt pipe.
  // Q folds 1/sqrt(DK) * log2(e) so softmax runs in base-2.
  gemm_qkv<<<dim3(M_ / 128, D_ / 128, 3), 256, 0, stream>>>(
      xq, xk, xv, wqb, wkb, wvb, bq, bk, bv, Qf, Kf, Vtb,
      0.125f * 1.4426950408889634f);

  attn_fwd<<<dim3(512), 512, 0, stream>>>(Qf, Kf, Vtb, AO);

  gemm_o<<<dim3(M_ / 128, D_ / 128), 512, 0, stream>>>(AO, wob, bo, (float*)d_out);
}